// Round 4
// baseline (552.845 us; speedup 1.0000x reference)
//
#include <hip/hip_runtime.h>

// Problem constants
#define BB 16
#define CC 128
#define PP 512
#define TT 32
#define HH 2
#define DD 64
#define EE 2048        // D*T
#define NPIX 16384     // P*T
#define SCALE 0.125f   // D^-0.5

typedef _Float16 f16_t;
typedef _Float16 f16x8_t __attribute__((ext_vector_type(8)));
typedef _Float16 f16x4_t __attribute__((ext_vector_type(4)));
typedef float    f32x4_t __attribute__((ext_vector_type(4)));

#define AS_GLOBAL __attribute__((address_space(1)))
#define AS_LDS    __attribute__((address_space(3)))

// Async global->LDS DMA, 16 B per lane. LDS dest is wave-uniform base;
// lane i's 16 B land at base + i*16 (HW-defined, m104/m108).
__device__ __forceinline__ void async_ld16(const void* g, void* l) {
    __builtin_amdgcn_global_load_lds((const AS_GLOBAL void*)g,
                                     (AS_LDS void*)l, 16, 0, 0);
}

// ---------------------------------------------------------------------------
// Double-buffered LDS-staged GEMM core (T3-minimum 2-phase pipeline):
// C(128x128) = A[M x K] @ Bt[N x K]^T.  256 threads / 4 waves; wave = 64x64
// (4x4 of 16x16x32 MFMA).  BK=64: 8 k-chunks of 8 f16 per tile.
// LDS per buffer per matrix: chunk-major, slot s = chunk*128 + row holds
// row's fp16[chunk*8 .. chunk*8+8) -- contiguous in lane order for
// global_load_lds AND phase-minimal on the 64-lane ds_read_b128.
// Pipeline: STAGE(next tile) is issued BEFORE the ds_read+MFMA of the
// current tile; the single __syncthreads() per step hides most of the load
// latency under the compute phase.
// MFMA lane mapping (HW-verified): A[m=lane&15][k=quad*8+j],
// B[k=quad*8+j][n=lane&15], D[row=quad*4+reg][col=lane&15].
// ---------------------------------------------------------------------------
template<int BK>
__device__ __forceinline__ void gemm_lds_bt_db(const f16_t* __restrict__ A, int lda,
                                               const f16_t* __restrict__ Bt, int ldb,
                                               int K, int m0, int n0,
                                               f16_t* As, f16_t* Bs,  // each 2*128*BK f16
                                               f32x4_t acc[4][4])
{
    const int tid  = threadIdx.x;
    const int lane = tid & 63;
    const int wave = tid >> 6;
    const int wm = wave & 1, wn = wave >> 1;
    const int quad = lane >> 4, l16 = lane & 15;

    constexpr int NCH  = BK / 8;        // k-chunks per tile
    constexpr int CPW  = NCH / 4;       // chunks handled per wave
    constexpr int TILE = 128 * BK;      // f16 per buffer per matrix

    const int ar = wm * 64 + l16;
    const int br = wn * 64 + l16;

    auto stage = [&](int buf, int k0) {
        f16_t* dA = As + buf * TILE;
        f16_t* dB = Bs + buf * TILE;
#pragma unroll
        for (int cc = 0; cc < CPW; ++cc) {
            const int ch = wave * CPW + cc;
            const int kk = k0 + ch * 8;
            async_ld16(A  + (size_t)(m0 + lane)      * lda + kk,
                       dA + (size_t)(ch * 128)       * 8);
            async_ld16(A  + (size_t)(m0 + 64 + lane) * lda + kk,
                       dA + (size_t)(ch * 128 + 64)  * 8);
            async_ld16(Bt + (size_t)(n0 + lane)      * ldb + kk,
                       dB + (size_t)(ch * 128)       * 8);
            async_ld16(Bt + (size_t)(n0 + 64 + lane) * ldb + kk,
                       dB + (size_t)(ch * 128 + 64)  * 8);
        }
    };

    stage(0, 0);
    __syncthreads();                    // prologue drain

    int cur = 0;
    for (int k0 = 0; k0 < K; k0 += BK) {
        if (k0 + BK < K) stage(cur ^ 1, k0 + BK);   // prefetch next tile

        const f16_t* sA = As + cur * TILE;
        const f16_t* sB = Bs + cur * TILE;
#pragma unroll
        for (int kk = 0; kk < BK / 32; ++kk) {
            const int chq = kk * 4 + quad;
            f16x8_t af[4], bf[4];
#pragma unroll
            for (int mi = 0; mi < 4; ++mi)
                af[mi] = *(const f16x8_t*)(sA + (size_t)(chq * 128 + ar + mi * 16) * 8);
#pragma unroll
            for (int ni = 0; ni < 4; ++ni)
                bf[ni] = *(const f16x8_t*)(sB + (size_t)(chq * 128 + br + ni * 16) * 8);
#pragma unroll
            for (int mi = 0; mi < 4; ++mi)
#pragma unroll
                for (int ni = 0; ni < 4; ++ni)
                    acc[mi][ni] = __builtin_amdgcn_mfma_f32_16x16x32_f16(
                        af[mi], bf[ni], acc[mi][ni], 0, 0, 0);
        }
        __syncthreads();                // waits prefetch (vmcnt0) + lgkm + barrier
        cur ^= 1;
    }
}

// ---------------------------------------------------------------------------
// Kernel 0: W fp32 -> fp16 (one-time, 49152 elems). Wh parked in the S
// region of the workspace (S isn't written until qk_kernel, after proj).
// ---------------------------------------------------------------------------
__global__ __launch_bounds__(256) void wcvt_kernel(const float* __restrict__ W,
                                                   f16_t* __restrict__ Wh)
{
    const int i = (blockIdx.x * 256 + threadIdx.x) * 4;
    const float4 wv = *(const float4*)(W + i);
    f16x4_t t;
    t[0] = (_Float16)wv.x; t[1] = (_Float16)wv.y;
    t[2] = (_Float16)wv.z; t[3] = (_Float16)wv.w;
    *(f16x4_t*)(Wh + i) = t;
}

// ---------------------------------------------------------------------------
// Kernel 1: QKV projection, v3 (occupancy fix).
// Round-3 analysis: acc[4][4] = 64 AGPR + 124 arch ~= 188 regs -> 2
// waves/SIMD (21.6% measured) -> stage/compute/epilogue phases can't
// overlap across blocks -> 2.4x over the ~54us BW floor.
// v3: wave tile 64o x 32pix (acc[4][2] = 32 AGPR), block = 2x2 waves =
// 128o x 64pix, LDS 16 KB, __launch_bounds__(256,3) -> 3 waves/SIMD,
// 3 blocks/CU; phases of co-resident blocks overlap, BW saturates.
// Same fragments, same MFMA order -> bit-identical output.
// grid (256, 16), block 256.
// ---------------------------------------------------------------------------
__global__ __launch_bounds__(256, 3) void proj_kernel(const float* __restrict__ x,
                                                      const f16_t* __restrict__ Wh,
                                                      const float* __restrict__ bias,
                                                      f16_t* __restrict__ q,
                                                      f16_t* __restrict__ k,
                                                      f16_t* __restrict__ v)
{
    __shared__ f16_t xs[CC * 64];           // swizzled [pix][c] fp16, 16 KB
    const int b    = blockIdx.y;
    const int pt   = blockIdx.x;            // 0..255
    const int tid  = threadIdx.x;
    const int lane = tid & 63;
    const int wave = tid >> 6;
    const int wm   = wave & 1, wn = wave >> 1;   // 2 (o) x 2 (pix)
    const int quad = lane >> 4, l16 = lane & 15;
    const int pixb = pt * 64;

    const float* xb = x + (size_t)b * CC * NPIX;

    // Stage + transpose + convert: unit u = c-octet (16 total); lanes are
    // 64 consecutive pix (coalesced 256B per load inst); each thread packs
    // 8 consecutive c for its pixel -> 1 swizzled ds_write_b128.
#pragma unroll
    for (int r = 0; r < 4; ++r) {
        const int u  = r * 4 + wave;        // 0..15
        const int c0 = u * 8;               // 0,8,...,120
        const int pl = lane;                // 0..63
        const float* g = xb + (size_t)c0 * NPIX + pixb + pl;
        float vv[8];
#pragma unroll
        for (int j = 0; j < 8; ++j) vv[j] = g[(size_t)j * NPIX];
        f16x8_t t;
#pragma unroll
        for (int j = 0; j < 8; ++j) t[j] = (_Float16)vv[j];
        *(f16x8_t*)((char*)xs + pl * 256 + ((c0 * 2) ^ ((pl & 15) << 4))) = t;
    }
    __syncthreads();

    for (int s = 0; s < 3; ++s) {
        f32x4_t acc[4][2];
#pragma unroll
        for (int i = 0; i < 4; ++i)
#pragma unroll
            for (int j = 0; j < 2; ++j) acc[i][j] = (f32x4_t){0.f, 0.f, 0.f, 0.f};

#pragma unroll
        for (int k0 = 0; k0 < CC; k0 += 32) {
            const int kq = k0 + quad * 8;
            f16x8_t af[4], bf[2];
#pragma unroll
            for (int mi = 0; mi < 4; ++mi) {
                const int o = s * 128 + wm * 64 + mi * 16 + l16;
                af[mi] = *(const f16x8_t*)(Wh + (size_t)o * CC + kq);
            }
#pragma unroll
            for (int ni = 0; ni < 2; ++ni) {
                const int pl = wn * 32 + ni * 16 + l16;
                bf[ni] = *(const f16x8_t*)((char*)xs + pl * 256 +
                                           ((kq * 2) ^ ((pl & 15) << 4)));
            }
#pragma unroll
            for (int mi = 0; mi < 4; ++mi)
#pragma unroll
                for (int ni = 0; ni < 2; ++ni)
                    acc[mi][ni] = __builtin_amdgcn_mfma_f32_16x16x32_f16(
                        af[mi], bf[ni], acc[mi][ni], 0, 0, 0);
        }

        f16_t* dst = (s == 0) ? q : (s == 1) ? k : v;
#pragma unroll
        for (int mi = 0; mi < 4; ++mi) {
#pragma unroll
            for (int r = 0; r < 4; ++r) {
                const int o_loc = wm * 64 + mi * 16 + quad * 4 + r;
                const int o     = s * 128 + o_loc;
                const float bv  = bias[o];
                const int h = o_loc >> 6, d = o_loc & 63;
#pragma unroll
                for (int ni = 0; ni < 2; ++ni) {
                    const int pix = pixb + wn * 32 + ni * 16 + l16;
                    const int p = pix >> 5, t = pix & 31;
                    const size_t addr =
                        ((size_t)((b * HH + h) * PP + p)) * EE + d * TT + t;
                    dst[addr] = (_Float16)(acc[mi][ni][r] + bv);
                }
            }
        }
    }
}

// ---------------------------------------------------------------------------
// Kernel 2: transpose v [bh][p][e] -> vt [bh][e][p] (64x64 LDS tiles).
// 16 B/lane global on BOTH sides; LDS side is scalar u16 ops (cheap).
// ---------------------------------------------------------------------------
__global__ __launch_bounds__(256) void vpose_kernel(const f16_t* __restrict__ v,
                                                    f16_t* __restrict__ vt)
{
    __shared__ unsigned short lds[64][65];
    const int bh   = blockIdx.y;
    const int tile = blockIdx.x;
    const int e0 = (tile & 31) * 64;
    const int p0 = (tile >> 5) * 64;
    const int tid = threadIdx.x;
    const int rw  = tid >> 3;          // 0..31
    const int c8  = (tid & 7) * 8;     // 0..56
    const f16_t* vb  = v  + (size_t)bh * PP * EE;
    f16_t*       vtb = vt + (size_t)bh * EE * PP;
#pragma unroll
    for (int half = 0; half < 2; ++half) {
        const int p = rw + half * 32;
        const f16x8_t t = *(const f16x8_t*)(vb + (size_t)(p0 + p) * EE + e0 + c8);
#pragma unroll
        for (int j = 0; j < 8; ++j)
            lds[p][c8 + j] = __builtin_bit_cast(unsigned short, (_Float16)t[j]);
    }
    __syncthreads();
#pragma unroll
    for (int half = 0; half < 2; ++half) {
        const int e = rw + half * 32;
        f16x8_t t;
#pragma unroll
        for (int j = 0; j < 8; ++j)
            t[j] = __builtin_bit_cast(_Float16, lds[c8 + j][e]);
        *(f16x8_t*)(vtb + (size_t)(e0 + e) * PP + p0 + c8) = t;
    }
}

// ---------------------------------------------------------------------------
// Kernel 3: S = SCALE * Q @ K^T per (b,h). M=N=512, K=2048.
// grid 512 blocks 1D: bh = id&31 (same bh -> same XCD), tile = id>>5.
// BK=64 double-buffered: 32 steps, 1 barrier each.
// ---------------------------------------------------------------------------
__global__ __launch_bounds__(256) void qk_kernel(const f16_t* __restrict__ q,
                                                 const f16_t* __restrict__ k,
                                                 float* __restrict__ S)
{
    __shared__ f16_t As[2 * 128 * 64];
    __shared__ f16_t Bs[2 * 128 * 64];
    const int id = blockIdx.x;
    const int bh = id & 31;
    const int tile = id >> 5;               // 0..15
    const int mt = tile & 3, nt = tile >> 2;
    const int tid  = threadIdx.x;
    const int lane = tid & 63;
    const int wave = tid >> 6;
    const int wm = wave & 1, wn = wave >> 1;
    const int quad = lane >> 4, l16 = lane & 15;

    f32x4_t acc[4][4];
#pragma unroll
    for (int i = 0; i < 4; ++i)
#pragma unroll
        for (int j = 0; j < 4; ++j) acc[i][j] = (f32x4_t){0.f, 0.f, 0.f, 0.f};

    const f16_t* qb = q + (size_t)bh * PP * EE;
    const f16_t* kb = k + (size_t)bh * PP * EE;
    gemm_lds_bt_db<64>(qb, EE, kb, EE, EE, mt * 128, nt * 128, As, Bs, acc);

    float* Sb = S + (size_t)bh * PP * PP;
#pragma unroll
    for (int mi = 0; mi < 4; ++mi)
#pragma unroll
        for (int r = 0; r < 4; ++r) {
            const int row = mt * 128 + wm * 64 + mi * 16 + quad * 4 + r;
#pragma unroll
            for (int ni = 0; ni < 4; ++ni) {
                const int col = nt * 128 + wn * 64 + ni * 16 + l16;
                Sb[(size_t)row * PP + col] = acc[mi][ni][r] * SCALE;
            }
        }
}

// ---------------------------------------------------------------------------
// Kernel 4: row softmax over S, writing normalized P as fp16 overlaid into
// S's storage (row pitch 1024 fp16 = 2048 B). One wave per row.
// ---------------------------------------------------------------------------
__global__ __launch_bounds__(256) void softmax_kernel(float* __restrict__ S)
{
    const int tid  = threadIdx.x;
    const int wave = tid >> 6;
    const int lane = tid & 63;
    const int row  = blockIdx.x * 4 + wave;
    float* rp = S + (size_t)row * PP;

    const float4 a = *(const float4*)(rp + lane * 8);
    const float4 b = *(const float4*)(rp + lane * 8 + 4);

    float m = fmaxf(fmaxf(fmaxf(a.x, a.y), fmaxf(a.z, a.w)),
                    fmaxf(fmaxf(b.x, b.y), fmaxf(b.z, b.w)));
#pragma unroll
    for (int off = 1; off < 64; off <<= 1) m = fmaxf(m, __shfl_xor(m, off, 64));

    float e[8];
    e[0] = expf(a.x - m); e[1] = expf(a.y - m);
    e[2] = expf(a.z - m); e[3] = expf(a.w - m);
    e[4] = expf(b.x - m); e[5] = expf(b.y - m);
    e[6] = expf(b.z - m); e[7] = expf(b.w - m);

    float sum = e[0] + e[1] + e[2] + e[3] + e[4] + e[5] + e[6] + e[7];
#pragma unroll
    for (int off = 1; off < 64; off <<= 1) sum += __shfl_xor(sum, off, 64);
    const float inv = 1.0f / sum;

    __syncthreads();   // order the fp16 stores after all float loads

    f16_t* prow = (f16_t*)rp;
    f16x8_t o;
#pragma unroll
    for (int j = 0; j < 8; ++j) o[j] = (_Float16)(e[j] * inv);
    *(f16x8_t*)(prow + lane * 8) = o;
}

// ---------------------------------------------------------------------------
// Kernel 5: O = P @ V per (b,h) -> out fp32 (b,c,p,t).
// A = P (pitch 1024 fp16), B = vt [e][p]. M=512, N=2048, K=512.
// grid 2048 blocks 1D: bh = id&31, tile = id>>5 (mt = tile&3, nt = tile>>2).
// BK=64 double-buffered: 8 steps.
// ---------------------------------------------------------------------------
__global__ __launch_bounds__(256) void pv_kernel(const f16_t* __restrict__ Pm,
                                                 const f16_t* __restrict__ vt,
                                                 float* __restrict__ out)
{
    __shared__ f16_t As[2 * 128 * 64];
    __shared__ f16_t Bs[2 * 128 * 64];
    const int id = blockIdx.x;
    const int bh = id & 31;
    const int tile = id >> 5;               // 0..63
    const int mt = tile & 3, nt = tile >> 2;
    const int tid  = threadIdx.x;
    const int lane = tid & 63;
    const int wave = tid >> 6;
    const int wm = wave & 1, wn = wave >> 1;
    const int quad = lane >> 4, l16 = lane & 15;

    f32x4_t acc[4][4];
#pragma unroll
    for (int i = 0; i < 4; ++i)
#pragma unroll
        for (int j = 0; j < 4; ++j) acc[i][j] = (f32x4_t){0.f, 0.f, 0.f, 0.f};

    const f16_t* Pb  = Pm + (size_t)bh * PP * 1024;
    const f16_t* vtb = vt + (size_t)bh * EE * PP;
    gemm_lds_bt_db<64>(Pb, 1024, vtb, PP, PP, mt * 128, nt * 128, As, Bs, acc);

    const int b = bh >> 1, h = bh & 1;
#pragma unroll
    for (int mi = 0; mi < 4; ++mi)
#pragma unroll
        for (int r = 0; r < 4; ++r) {
            const int p = mt * 128 + wm * 64 + mi * 16 + quad * 4 + r;
#pragma unroll
            for (int ni = 0; ni < 4; ++ni) {
                const int e = nt * 128 + wn * 64 + ni * 16 + l16;
                const int d = e >> 5, t = e & 31;
                out[(((size_t)(b * CC + h * DD + d)) * PP + p) * TT + t] =
                    acc[mi][ni][r];
            }
        }
}

// ---------------------------------------------------------------------------
// Workspace layout (bytes):
//   [0,   64M)  q   fp16 [b][h][p][e]
//   [64M, 128M) k   fp16 [b][h][p][e]
//   [128M,192M) v   fp16 [b][h][p][e]
//   [192M,256M) vt  fp16 [b][h][e][p]
//   [256M,288M) S   fp32 [bh][i][j]  (P fp16 overlaid, row pitch 1024 elems)
//   Wh fp16 [384][128] parked at 256M (S region) -- consumed by proj before
//   qk_kernel overwrites it with S.
// ---------------------------------------------------------------------------
extern "C" void kernel_launch(void* const* d_in, const int* in_sizes, int n_in,
                              void* d_out, int out_size, void* d_ws, size_t ws_size,
                              hipStream_t stream)
{
    const float* x    = (const float*)d_in[0];
    const float* W    = (const float*)d_in[1];
    const float* bias = (const float*)d_in[2];
    float* out = (float*)d_out;

    char* ws = (char*)d_ws;
    const size_t MiB = 1024ull * 1024ull;
    f16_t* q  = (f16_t*)(ws);
    f16_t* k  = (f16_t*)(ws + 64 * MiB);
    f16_t* v  = (f16_t*)(ws + 128 * MiB);
    f16_t* vt = (f16_t*)(ws + 192 * MiB);
    float* S  = (float*)(ws + 256 * MiB);
    f16_t* Wh = (f16_t*)(ws + 256 * MiB);   // overlaid with S (safe: see above)

    wcvt_kernel<<<dim3(48), dim3(256), 0, stream>>>(W, Wh);
    proj_kernel<<<dim3(256, 16), dim3(256), 0, stream>>>(x, Wh, bias, q, k, v);
    vpose_kernel<<<dim3(256, 32), dim3(256), 0, stream>>>(v, vt);
    qk_kernel<<<dim3(512), dim3(256), 0, stream>>>(q, k, S);
    softmax_kernel<<<dim3(4096), dim3(256), 0, stream>>>(S);
    pv_kernel<<<dim3(2048), dim3(256), 0, stream>>>((const f16_t*)S, vt, out);
}

// Round 5
// 503.258 us; speedup vs baseline: 1.0985x; 1.0985x over previous
//
#include <hip/hip_runtime.h>

// Problem constants
#define BB 16
#define CC 128
#define PP 512
#define TT 32
#define HH 2
#define DD 64
#define EE 2048        // D*T
#define NPIX 16384     // P*T
#define SCALE 0.125f   // D^-0.5

typedef _Float16 f16_t;
typedef _Float16 f16x8_t __attribute__((ext_vector_type(8)));
typedef _Float16 f16x4_t __attribute__((ext_vector_type(4)));
typedef float    f32x4_t __attribute__((ext_vector_type(4)));

#define AS_GLOBAL __attribute__((address_space(1)))
#define AS_LDS    __attribute__((address_space(3)))

// Async global->LDS DMA, 16 B per lane. LDS dest is wave-uniform base;
// lane i's 16 B land at base + i*16 (HW-defined, m104/m108).
__device__ __forceinline__ void async_ld16(const void* g, void* l) {
    __builtin_amdgcn_global_load_lds((const AS_GLOBAL void*)g,
                                     (AS_LDS void*)l, 16, 0, 0);
}

// ---------------------------------------------------------------------------
// LDS-staged GEMM core (m97 structure, single-buffer BK=32 -- round-3's
// explicit dbuf was a 13us regression, reverted): C(128x128) = A @ Bt^T.
// 256 threads / 4 waves; wave = 64x64 (4x4 of 16x16x32 MFMA).
// LDS tile: chunk-major, slot s = chunk*128 + row holds row's
// fp16[chunk*8..chunk*8+8) -- contiguous in lane order for global_load_lds
// and phase-minimal on the 64-lane ds_read_b128.
// MFMA lane mapping (HW-verified): A[m=lane&15][k=quad*8+j],
// B[k=quad*8+j][n=lane&15], D[row=quad*4+reg][col=lane&15].
// ---------------------------------------------------------------------------
__device__ __forceinline__ void gemm_lds_bt(const f16_t* __restrict__ A, int lda,
                                            const f16_t* __restrict__ Bt, int ldb,
                                            int K, int m0, int n0,
                                            f16_t* As, f16_t* Bs,
                                            f32x4_t acc[4][4])
{
    const int tid  = threadIdx.x;
    const int lane = tid & 63;
    const int wave = tid >> 6;
    const int wm = wave & 1, wn = wave >> 1;
    const int quad = lane >> 4, l16 = lane & 15;

    const f16_t* gA0 = A  + (size_t)(m0 + lane)      * lda + wave * 8;
    const f16_t* gA1 = A  + (size_t)(m0 + 64 + lane) * lda + wave * 8;
    const f16_t* gB0 = Bt + (size_t)(n0 + lane)      * ldb + wave * 8;
    const f16_t* gB1 = Bt + (size_t)(n0 + 64 + lane) * ldb + wave * 8;
    f16_t* lA0 = As + (size_t)(wave * 128)      * 8;
    f16_t* lA1 = As + (size_t)(wave * 128 + 64) * 8;
    f16_t* lB0 = Bs + (size_t)(wave * 128)      * 8;
    f16_t* lB1 = Bs + (size_t)(wave * 128 + 64) * 8;

    const int ar = wm * 64 + l16;
    const int br = wn * 64 + l16;

    for (int k0 = 0; k0 < K; k0 += 32) {
        if (k0) __syncthreads();            // prior iter's LDS reads done
        async_ld16(gA0 + k0, lA0);
        async_ld16(gA1 + k0, lA1);
        async_ld16(gB0 + k0, lB0);
        async_ld16(gB1 + k0, lB1);
        __syncthreads();                    // vmcnt(0) drain + barrier

        f16x8_t af[4], bf[4];
#pragma unroll
        for (int mi = 0; mi < 4; ++mi)
            af[mi] = *(const f16x8_t*)(As + (size_t)(quad * 128 + ar + mi * 16) * 8);
#pragma unroll
        for (int ni = 0; ni < 4; ++ni)
            bf[ni] = *(const f16x8_t*)(Bs + (size_t)(quad * 128 + br + ni * 16) * 8);
#pragma unroll
        for (int mi = 0; mi < 4; ++mi)
#pragma unroll
            for (int ni = 0; ni < 4; ++ni)
                acc[mi][ni] = __builtin_amdgcn_mfma_f32_16x16x32_f16(
                    af[mi], bf[ni], acc[mi][ni], 0, 0, 0);
    }
}

// ---------------------------------------------------------------------------
// Kernel 0: W fp32 -> fp16 (one-time, 49152 elems). Wh parked in the S
// region of the workspace (S isn't written until qk_kernel, after proj).
// ---------------------------------------------------------------------------
__global__ __launch_bounds__(256) void wcvt_kernel(const float* __restrict__ W,
                                                   f16_t* __restrict__ Wh)
{
    const int i = (blockIdx.x * 256 + threadIdx.x) * 4;
    const float4 wv = *(const float4*)(W + i);
    f16x4_t t;
    t[0] = (_Float16)wv.x; t[1] = (_Float16)wv.y;
    t[2] = (_Float16)wv.z; t[3] = (_Float16)wv.w;
    *(f16x4_t*)(Wh + i) = t;
}

// ---------------------------------------------------------------------------
// Kernel 1: QKV projection, v4 (store-issue fix via operand swap).
// Round-4 post-mortem: proj is STORE-ISSUE-bound -- the old epilogue was
// 192 scalar 2B stores/thread (100M insts/dispatch) because per-thread r
// advanced along o (memory-strided). Swap MFMA operands:
// mfma(x_frag, w_frag) -> D[row=pix][col=o]; fragments are the SAME loads
// (xs is [pix][c], Wh is [o][c]), products and sum order identical ->
// bit-identical output -- but r now advances along t (contiguous) ->
// packed f16x4 8B stores, 48/thread (4x fewer, 4x wider).
// Structure otherwise = round-2 (best measured: 129us): 128c x 128pix
// staged once (fp16, [pix][c], XOR-swizzled, 32 KB), s=0..2 loop.
// grid (128, 16), block 256.
// ---------------------------------------------------------------------------
__global__ __launch_bounds__(256) void proj_kernel(const float* __restrict__ x,
                                                   const f16_t* __restrict__ Wh,
                                                   const float* __restrict__ bias,
                                                   f16_t* __restrict__ q,
                                                   f16_t* __restrict__ k,
                                                   f16_t* __restrict__ v)
{
    __shared__ f16_t xs[CC * 128];          // swizzled [pix][c] fp16, 32 KB
    const int b    = blockIdx.y;
    const int pt   = blockIdx.x;
    const int tid  = threadIdx.x;
    const int lane = tid & 63;
    const int wave = tid >> 6;
    const int wm   = wave & 1, wn = wave >> 1;   // wm: pix half, wn: o half
    const int quad = lane >> 4, l16 = lane & 15;
    const int pixb = pt * 128;

    const float* xb = x + (size_t)b * CC * NPIX;

    // Stage + transpose + convert: unit u = (c-octet, pix-half).
    // Loads are coalesced (lanes = consecutive pix, 256B/inst); each lane
    // packs 8 consecutive c for its pixel -> 1 swizzled ds_write_b128.
#pragma unroll 2
    for (int r = 0; r < 8; ++r) {
        const int u  = r * 4 + wave;        // 0..31
        const int c0 = (u >> 1) * 8;        // 0,8,...,120
        const int pl = (u & 1) * 64 + lane; // 0..127
        const float* g = xb + (size_t)c0 * NPIX + pixb + pl;
        float vv[8];
#pragma unroll
        for (int j = 0; j < 8; ++j) vv[j] = g[(size_t)j * NPIX];
        f16x8_t t;
#pragma unroll
        for (int j = 0; j < 8; ++j) t[j] = (_Float16)vv[j];
        *(f16x8_t*)((char*)xs + pl * 256 + ((c0 * 2) ^ ((pl & 15) << 4))) = t;
    }
    __syncthreads();

    for (int s = 0; s < 3; ++s) {
        f32x4_t acc[4][4];                  // [mi: pix tiles][ni: o tiles]
#pragma unroll
        for (int i = 0; i < 4; ++i)
#pragma unroll
            for (int j = 0; j < 4; ++j) acc[i][j] = (f32x4_t){0.f, 0.f, 0.f, 0.f};

#pragma unroll
        for (int k0 = 0; k0 < CC; k0 += 32) {
            const int kq = k0 + quad * 8;
            f16x8_t xf[4], wf[4];
#pragma unroll
            for (int mi = 0; mi < 4; ++mi) {           // A = x[pix][c]
                const int pl = wm * 64 + mi * 16 + l16;
                xf[mi] = *(const f16x8_t*)((char*)xs + pl * 256 +
                                           ((kq * 2) ^ ((pl & 15) << 4)));
            }
#pragma unroll
            for (int ni = 0; ni < 4; ++ni) {           // B = W[o][c]
                const int o = s * 128 + wn * 64 + ni * 16 + l16;
                wf[ni] = *(const f16x8_t*)(Wh + (size_t)o * CC + kq);
            }
#pragma unroll
            for (int mi = 0; mi < 4; ++mi)
#pragma unroll
                for (int ni = 0; ni < 4; ++ni)
                    acc[mi][ni] = __builtin_amdgcn_mfma_f32_16x16x32_f16(
                        xf[mi], wf[ni], acc[mi][ni], 0, 0, 0);
        }

        f16_t* dst = (s == 0) ? q : (s == 1) ? k : v;
        // bias per (s, ni): o depends on l16 -> per-lane vector load.
        float bv[4];
#pragma unroll
        for (int ni = 0; ni < 4; ++ni)
            bv[ni] = bias[s * 128 + wn * 64 + ni * 16 + l16];

        const int h = wn;                   // o_local>>6
#pragma unroll
        for (int mi = 0; mi < 4; ++mi) {
            const int pix0 = pixb + wm * 64 + mi * 16 + quad * 4;  // r = 0..3
            const int p  = pix0 >> 5;
            const int t0 = pix0 & 31;       // multiple of 4 -> 8B aligned
#pragma unroll
            for (int ni = 0; ni < 4; ++ni) {
                const int d = ni * 16 + l16;
                f16x4_t o4;
#pragma unroll
                for (int r = 0; r < 4; ++r)
                    o4[r] = (_Float16)(acc[mi][ni][r] + bv[ni]);
                *(f16x4_t*)(dst + ((size_t)((b * HH + h) * PP + p)) * EE
                                + d * TT + t0) = o4;
            }
        }
    }
}

// ---------------------------------------------------------------------------
// Kernel 2: transpose v [bh][p][e] -> vt [bh][e][p] (64x64 LDS tiles).
// 16 B/lane global on BOTH sides; LDS side is scalar u16 ops (cheap).
// ---------------------------------------------------------------------------
__global__ __launch_bounds__(256) void vpose_kernel(const f16_t* __restrict__ v,
                                                    f16_t* __restrict__ vt)
{
    __shared__ unsigned short lds[64][65];
    const int bh   = blockIdx.y;
    const int tile = blockIdx.x;
    const int e0 = (tile & 31) * 64;
    const int p0 = (tile >> 5) * 64;
    const int tid = threadIdx.x;
    const int rw  = tid >> 3;          // 0..31
    const int c8  = (tid & 7) * 8;     // 0..56
    const f16_t* vb  = v  + (size_t)bh * PP * EE;
    f16_t*       vtb = vt + (size_t)bh * EE * PP;
#pragma unroll
    for (int half = 0; half < 2; ++half) {
        const int p = rw + half * 32;
        const f16x8_t t = *(const f16x8_t*)(vb + (size_t)(p0 + p) * EE + e0 + c8);
#pragma unroll
        for (int j = 0; j < 8; ++j)
            lds[p][c8 + j] = __builtin_bit_cast(unsigned short, (_Float16)t[j]);
    }
    __syncthreads();
#pragma unroll
    for (int half = 0; half < 2; ++half) {
        const int e = rw + half * 32;
        f16x8_t t;
#pragma unroll
        for (int j = 0; j < 8; ++j)
            t[j] = __builtin_bit_cast(_Float16, lds[c8 + j][e]);
        *(f16x8_t*)(vtb + (size_t)(e0 + e) * PP + p0 + c8) = t;
    }
}

// ---------------------------------------------------------------------------
// Kernel 3: S = SCALE * Q @ K^T per (b,h). M=N=512, K=2048.
// grid 512 blocks 1D: bh = id&31 (same bh -> same XCD), tile = id>>5.
// Epilogue is scalar f32 stores (row-strided; not packable) -- issue floor
// here is only ~13us, acceptable.
// ---------------------------------------------------------------------------
__global__ __launch_bounds__(256) void qk_kernel(const f16_t* __restrict__ q,
                                                 const f16_t* __restrict__ k,
                                                 float* __restrict__ S)
{
    __shared__ f16_t As[128 * 32];
    __shared__ f16_t Bs[128 * 32];
    const int id = blockIdx.x;
    const int bh = id & 31;
    const int tile = id >> 5;               // 0..15
    const int mt = tile & 3, nt = tile >> 2;
    const int tid  = threadIdx.x;
    const int lane = tid & 63;
    const int wave = tid >> 6;
    const int wm = wave & 1, wn = wave >> 1;
    const int quad = lane >> 4, l16 = lane & 15;

    f32x4_t acc[4][4];
#pragma unroll
    for (int i = 0; i < 4; ++i)
#pragma unroll
        for (int j = 0; j < 4; ++j) acc[i][j] = (f32x4_t){0.f, 0.f, 0.f, 0.f};

    const f16_t* qb = q + (size_t)bh * PP * EE;
    const f16_t* kb = k + (size_t)bh * PP * EE;
    gemm_lds_bt(qb, EE, kb, EE, EE, mt * 128, nt * 128, As, Bs, acc);

    float* Sb = S + (size_t)bh * PP * PP;
#pragma unroll
    for (int mi = 0; mi < 4; ++mi)
#pragma unroll
        for (int r = 0; r < 4; ++r) {
            const int row = mt * 128 + wm * 64 + mi * 16 + quad * 4 + r;
#pragma unroll
            for (int ni = 0; ni < 4; ++ni) {
                const int col = nt * 128 + wn * 64 + ni * 16 + l16;
                Sb[(size_t)row * PP + col] = acc[mi][ni][r] * SCALE;
            }
        }
}

// ---------------------------------------------------------------------------
// Kernel 4: row softmax over S, writing normalized P as fp16 overlaid into
// S's storage (row pitch 1024 fp16 = 2048 B). One wave per row.
// ---------------------------------------------------------------------------
__global__ __launch_bounds__(256) void softmax_kernel(float* __restrict__ S)
{
    const int tid  = threadIdx.x;
    const int wave = tid >> 6;
    const int lane = tid & 63;
    const int row  = blockIdx.x * 4 + wave;
    float* rp = S + (size_t)row * PP;

    const float4 a = *(const float4*)(rp + lane * 8);
    const float4 b = *(const float4*)(rp + lane * 8 + 4);

    float m = fmaxf(fmaxf(fmaxf(a.x, a.y), fmaxf(a.z, a.w)),
                    fmaxf(fmaxf(b.x, b.y), fmaxf(b.z, b.w)));
#pragma unroll
    for (int off = 1; off < 64; off <<= 1) m = fmaxf(m, __shfl_xor(m, off, 64));

    float e[8];
    e[0] = expf(a.x - m); e[1] = expf(a.y - m);
    e[2] = expf(a.z - m); e[3] = expf(a.w - m);
    e[4] = expf(b.x - m); e[5] = expf(b.y - m);
    e[6] = expf(b.z - m); e[7] = expf(b.w - m);

    float sum = e[0] + e[1] + e[2] + e[3] + e[4] + e[5] + e[6] + e[7];
#pragma unroll
    for (int off = 1; off < 64; off <<= 1) sum += __shfl_xor(sum, off, 64);
    const float inv = 1.0f / sum;

    __syncthreads();   // order the fp16 stores after all float loads

    f16_t* prow = (f16_t*)rp;
    f16x8_t o;
#pragma unroll
    for (int j = 0; j < 8; ++j) o[j] = (_Float16)(e[j] * inv);
    *(f16x8_t*)(prow + lane * 8) = o;
}

// ---------------------------------------------------------------------------
// Kernel 5: O = P @ V per (b,h) -> out fp32 (b,c,p,t), v2 (operand swap).
// Swapped roles: A = vt [e][q] (M = e = 2048), Bt = P (N = p = 512), K=512.
// D[row=e][col=p]: per-thread r advances along t (contiguous in out) ->
// one float4 16B store per (mi,ni): 16 stores/thread vs 64 scalar before,
// and zero format conversion (acc stored directly).
// grid 2048 blocks 1D: bh = id&31, tile = id>>5; nt=p-tile(0..3),
// mt=e-tile(0..15). Bit-identical sums (same products, same order).
// ---------------------------------------------------------------------------
__global__ __launch_bounds__(256) void pv_kernel(const f16_t* __restrict__ Pm,
                                                 const f16_t* __restrict__ vt,
                                                 float* __restrict__ out)
{
    __shared__ f16_t As[128 * 32];
    __shared__ f16_t Bs[128 * 32];
    const int id = blockIdx.x;
    const int bh = id & 31;
    const int tile = id >> 5;               // 0..63
    const int nt = tile & 3, mt = tile >> 2;
    const int tid  = threadIdx.x;
    const int lane = tid & 63;
    const int wave = tid >> 6;
    const int wm = wave & 1, wn = wave >> 1;
    const int quad = lane >> 4, l16 = lane & 15;

    f32x4_t acc[4][4];                      // [mi: e tiles][ni: p tiles]
#pragma unroll
    for (int i = 0; i < 4; ++i)
#pragma unroll
        for (int j = 0; j < 4; ++j) acc[i][j] = (f32x4_t){0.f, 0.f, 0.f, 0.f};

    const f16_t* Pb  = Pm + (size_t)bh * PP * 1024;
    const f16_t* vtb = vt + (size_t)bh * EE * PP;
    gemm_lds_bt(vtb, PP, Pb, 1024, PP, mt * 128, nt * 128, As, Bs, acc);

    const int b = bh >> 1, h = bh & 1;
#pragma unroll
    for (int mi = 0; mi < 4; ++mi) {
        const int e0 = mt * 128 + wm * 64 + mi * 16 + quad * 4;   // r = 0..3
        const int d  = e0 >> 5;
        const int t0 = e0 & 31;             // multiple of 4 -> 16B aligned
#pragma unroll
        for (int ni = 0; ni < 4; ++ni) {
            const int p = nt * 128 + wn * 64 + ni * 16 + l16;
            *(f32x4_t*)(out + ((size_t)(b * CC + h * DD + d) * PP + p) * TT + t0)
                = acc[mi][ni];
        }
    }
}

// ---------------------------------------------------------------------------
// Workspace layout (bytes):
//   [0,   64M)  q   fp16 [b][h][p][e]
//   [64M, 128M) k   fp16 [b][h][p][e]
//   [128M,192M) v   fp16 [b][h][p][e]
//   [192M,256M) vt  fp16 [b][h][e][p]
//   [256M,288M) S   fp32 [bh][i][j]  (P fp16 overlaid, row pitch 1024 elems)
//   Wh fp16 [384][128] parked at 256M (S region) -- consumed by proj before
//   qk_kernel overwrites it with S.
// ---------------------------------------------------------------------------
extern "C" void kernel_launch(void* const* d_in, const int* in_sizes, int n_in,
                              void* d_out, int out_size, void* d_ws, size_t ws_size,
                              hipStream_t stream)
{
    const float* x    = (const float*)d_in[0];
    const float* W    = (const float*)d_in[1];
    const float* bias = (const float*)d_in[2];
    float* out = (float*)d_out;

    char* ws = (char*)d_ws;
    const size_t MiB = 1024ull * 1024ull;
    f16_t* q  = (f16_t*)(ws);
    f16_t* k  = (f16_t*)(ws + 64 * MiB);
    f16_t* v  = (f16_t*)(ws + 128 * MiB);
    f16_t* vt = (f16_t*)(ws + 192 * MiB);
    float* S  = (float*)(ws + 256 * MiB);
    f16_t* Wh = (f16_t*)(ws + 256 * MiB);   // overlaid with S (safe: see above)

    wcvt_kernel<<<dim3(48), dim3(256), 0, stream>>>(W, Wh);
    proj_kernel<<<dim3(128, 16), dim3(256), 0, stream>>>(x, Wh, bias, q, k, v);
    vpose_kernel<<<dim3(256, 32), dim3(256), 0, stream>>>(v, vt);
    qk_kernel<<<dim3(512), dim3(256), 0, stream>>>(q, k, S);
    softmax_kernel<<<dim3(4096), dim3(256), 0, stream>>>(S);
    pv_kernel<<<dim3(2048), dim3(256), 0, stream>>>((const f16_t*)S, vt, out);
}

// Round 7
// 498.530 us; speedup vs baseline: 1.1089x; 1.0095x over previous
//
#include <hip/hip_runtime.h>

// Problem constants
#define BB 16
#define CC 128
#define PP 512
#define TT 32
#define HH 2
#define DD 64
#define EE 2048        // D*T
#define NPIX 16384     // P*T
#define SCALE 0.125f   // D^-0.5

typedef _Float16 f16_t;
typedef _Float16 f16x8_t __attribute__((ext_vector_type(8)));
typedef _Float16 f16x4_t __attribute__((ext_vector_type(4)));
typedef float    f32x4_t __attribute__((ext_vector_type(4)));

#define AS_GLOBAL __attribute__((address_space(1)))
#define AS_LDS    __attribute__((address_space(3)))

// Async global->LDS DMA, 16 B per lane. LDS dest is wave-uniform base;
// lane i's 16 B land at base + i*16 (HW-defined, m104/m108). Global source
// address is PER-LANE (m173) -- scatter-gather on the read side is legal.
__device__ __forceinline__ void async_ld16(const void* g, void* l) {
    __builtin_amdgcn_global_load_lds((const AS_GLOBAL void*)g,
                                     (AS_LDS void*)l, 16, 0, 0);
}

// ---------------------------------------------------------------------------
// LDS-staged GEMM core (m97 structure, single-buffer BK=32): C = A @ Bt^T.
// 256 threads / 4 waves; wave = 64x64 (4x4 of 16x16x32 MFMA).
// LDS tile: chunk-major, slot s = chunk*128 + row holds row's
// fp16[chunk*8..chunk*8+8) -- contiguous in lane order for global_load_lds
// and phase-minimal on the 64-lane ds_read_b128.
// MFMA lane mapping (HW-verified): A[m=lane&15][k=quad*8+j],
// B[k=quad*8+j][n=lane&15], D[row=quad*4+reg][col=lane&15].
// ---------------------------------------------------------------------------
__device__ __forceinline__ void gemm_lds_bt(const f16_t* __restrict__ A, int lda,
                                            const f16_t* __restrict__ Bt, int ldb,
                                            int K, int m0, int n0,
                                            f16_t* As, f16_t* Bs,
                                            f32x4_t acc[4][4])
{
    const int tid  = threadIdx.x;
    const int lane = tid & 63;
    const int wave = tid >> 6;
    const int wm = wave & 1, wn = wave >> 1;
    const int quad = lane >> 4, l16 = lane & 15;

    const f16_t* gA0 = A  + (size_t)(m0 + lane)      * lda + wave * 8;
    const f16_t* gA1 = A  + (size_t)(m0 + 64 + lane) * lda + wave * 8;
    const f16_t* gB0 = Bt + (size_t)(n0 + lane)      * ldb + wave * 8;
    const f16_t* gB1 = Bt + (size_t)(n0 + 64 + lane) * ldb + wave * 8;
    f16_t* lA0 = As + (size_t)(wave * 128)      * 8;
    f16_t* lA1 = As + (size_t)(wave * 128 + 64) * 8;
    f16_t* lB0 = Bs + (size_t)(wave * 128)      * 8;
    f16_t* lB1 = Bs + (size_t)(wave * 128 + 64) * 8;

    const int ar = wm * 64 + l16;
    const int br = wn * 64 + l16;

    for (int k0 = 0; k0 < K; k0 += 32) {
        if (k0) __syncthreads();            // prior iter's LDS reads done
        async_ld16(gA0 + k0, lA0);
        async_ld16(gA1 + k0, lA1);
        async_ld16(gB0 + k0, lB0);
        async_ld16(gB1 + k0, lB1);
        __syncthreads();                    // vmcnt(0) drain + barrier

        f16x8_t af[4], bf[4];
#pragma unroll
        for (int mi = 0; mi < 4; ++mi)
            af[mi] = *(const f16x8_t*)(As + (size_t)(quad * 128 + ar + mi * 16) * 8);
#pragma unroll
        for (int ni = 0; ni < 4; ++ni)
            bf[ni] = *(const f16x8_t*)(Bs + (size_t)(quad * 128 + br + ni * 16) * 8);
#pragma unroll
        for (int mi = 0; mi < 4; ++mi)
#pragma unroll
            for (int ni = 0; ni < 4; ++ni)
                acc[mi][ni] = __builtin_amdgcn_mfma_f32_16x16x32_f16(
                    af[mi], bf[ni], acc[mi][ni], 0, 0, 0);
    }
}

// ---------------------------------------------------------------------------
// Kernel 0: W fp32 -> fp16 (one-time, 49152 elems). Wh parked in the S
// region of the workspace (S isn't written until qk_kernel, after proj).
// ---------------------------------------------------------------------------
__global__ __launch_bounds__(256) void wcvt_kernel(const float* __restrict__ W,
                                                   f16_t* __restrict__ Wh)
{
    const int i = (blockIdx.x * 256 + threadIdx.x) * 4;
    const float4 wv = *(const float4*)(W + i);
    f16x4_t t;
    t[0] = (_Float16)wv.x; t[1] = (_Float16)wv.y;
    t[2] = (_Float16)wv.z; t[3] = (_Float16)wv.w;
    *(f16x4_t*)(Wh + i) = t;
}

// ---------------------------------------------------------------------------
// Kernel 1: QKV projection, v5 (kill the two residual scatter patterns).
// Round-5 post-mortem: r2 and r5 epilogues touch identical line counts
// (768 line-ops/wave) -- that's why 4x fewer store insts didn't help. The
// shared costs across ALL proj variants: (1) Wh K-loop loads = 16 L2
// line-requests per inst, 48/thread, latency-exposed inside the MFMA
// dependency chain at 2 waves/SIMD; (2) d-strided stores = 16 half-lines
// per inst.
// v5: (a) stage the per-s W slice (32 KB contiguous) into LDS wbuf in the
// gemm chunk-major layout via global_load_lds (per-lane SOURCE scatter,
// linear dest; read banks 2-way = free) -> K-loop is pure LDS+MFMA.
// (b) epilogue: acc -> obuf (32 KB, ALIASES wbuf, barrier-separated,
// layout [h][p][d][t], XOR ((d&3)<<4) swizzle) -> fully-coalesced
// 16B/lane global stores (16 complete lines per inst).
// Fragments, MFMA order, bias math identical -> bit-identical output.
// grid (128, 16), block 256. LDS 64 KB -> 2 blocks/CU (= reg limit).
// ---------------------------------------------------------------------------
__global__ __launch_bounds__(256) void proj_kernel(const float* __restrict__ x,
                                                   const f16_t* __restrict__ Wh,
                                                   const float* __restrict__ bias,
                                                   f16_t* __restrict__ q,
                                                   f16_t* __restrict__ k,
                                                   f16_t* __restrict__ v)
{
    __shared__ f16_t xs[CC * 128];          // swizzled [pix][c] fp16, 32 KB
    __shared__ f16_t wbuf[16 * 128 * 8];    // chunk-major W slice / obuf, 32 KB
    const int b    = blockIdx.y;
    const int pt   = blockIdx.x;
    const int tid  = threadIdx.x;
    const int lane = tid & 63;
    const int wave = tid >> 6;
    const int wm   = wave & 1, wn = wave >> 1;   // wm: pix half, wn: o half
    const int quad = lane >> 4, l16 = lane & 15;
    const int pixb = pt * 128;

    const float* xb = x + (size_t)b * CC * NPIX;

    // Stage x tile as fp16 transposed [pix][c], XOR-swizzled.
    // Loads coalesced (lanes = consecutive pix, 256B/inst); each lane packs
    // 8 consecutive c for its pixel -> 1 swizzled ds_write_b128.
#pragma unroll 2
    for (int r = 0; r < 8; ++r) {
        const int u  = r * 4 + wave;        // 0..31
        const int c0 = (u >> 1) * 8;        // 0,8,...,120
        const int pl = (u & 1) * 64 + lane; // 0..127
        const float* g = xb + (size_t)c0 * NPIX + pixb + pl;
        float vv[8];
#pragma unroll
        for (int j = 0; j < 8; ++j) vv[j] = g[(size_t)j * NPIX];
        f16x8_t t;
#pragma unroll
        for (int j = 0; j < 8; ++j) t[j] = (_Float16)vv[j];
        *(f16x8_t*)((char*)xs + pl * 256 + ((c0 * 2) ^ ((pl & 15) << 4))) = t;
    }
    // NOTE: no barrier here -- the first s-iteration's barrier (after wbuf
    // DMA issue) covers both xs completion and wbuf drain.

    for (int s = 0; s < 3; ++s) {
        // --- stage W slice s into wbuf, gemm chunk-major: slot ch*128+o
        // holds Wh[s*128+o][ch*8 .. ch*8+8). 32 insts/block, per-lane src.
#pragma unroll
        for (int i = 0; i < 8; ++i) {
            const int idx = wave * 8 + i;   // 0..31
            const int ch  = idx >> 1;       // 0..15
            const int oh  = (idx & 1) * 64; // 0 / 64
            async_ld16(Wh + (size_t)(s * 128 + oh + lane) * CC + ch * 8,
                       wbuf + ((size_t)ch * 128 + oh) * 8);
        }
        __syncthreads();                    // wbuf (and xs on s==0) ready

        f32x4_t acc[4][4];                  // [mi: pix tiles][ni: o tiles]
#pragma unroll
        for (int i = 0; i < 4; ++i)
#pragma unroll
            for (int j = 0; j < 4; ++j) acc[i][j] = (f32x4_t){0.f, 0.f, 0.f, 0.f};

#pragma unroll
        for (int k0 = 0; k0 < CC; k0 += 32) {
            const int kq  = k0 + quad * 8;
            const int chq = (k0 >> 3) + quad;          // = kq/8
            f16x8_t xf[4], wf[4];
#pragma unroll
            for (int mi = 0; mi < 4; ++mi) {           // A = x[pix][c]
                const int pl = wm * 64 + mi * 16 + l16;
                xf[mi] = *(const f16x8_t*)((char*)xs + pl * 256 +
                                           ((kq * 2) ^ ((pl & 15) << 4)));
            }
#pragma unroll
            for (int ni = 0; ni < 4; ++ni) {           // B = W[o][c] via LDS
                const int ol = wn * 64 + ni * 16 + l16;
                wf[ni] = *(const f16x8_t*)(wbuf + ((size_t)chq * 128 + ol) * 8);
            }
#pragma unroll
            for (int mi = 0; mi < 4; ++mi)
#pragma unroll
                for (int ni = 0; ni < 4; ++ni)
                    acc[mi][ni] = __builtin_amdgcn_mfma_f32_16x16x32_f16(
                        xf[mi], wf[ni], acc[mi][ni], 0, 0, 0);
        }

        // bias per (s, ni): o depends on l16 -> per-lane scalar load.
        float bv[4];
#pragma unroll
        for (int ni = 0; ni < 4; ++ni)
            bv[ni] = bias[s * 128 + wn * 64 + ni * 16 + l16];

        __syncthreads();                    // all wbuf K-loop reads done

        // --- acc -> obuf (aliases wbuf): elem ((h*4+p)*64+d)*32+t,
        // byte XOR ((d&3)<<4) (8B-aligned-preserving, bijective in t-row).
        f16_t* obuf = wbuf;
#pragma unroll
        for (int mi = 0; mi < 4; ++mi) {
            const int pixl = wm * 64 + mi * 16 + quad * 4;   // r = 0..3 -> t
            const int p  = pixl >> 5;
            const int t0 = pixl & 31;
#pragma unroll
            for (int ni = 0; ni < 4; ++ni) {
                const int d = ni * 16 + l16;
                f16x4_t o4;
#pragma unroll
                for (int r = 0; r < 4; ++r)
                    o4[r] = (_Float16)(acc[mi][ni][r] + bv[ni]);
                const int ebyte = (((wn * 4 + p) * 64 + d) * 32 + t0) * 2;
                *(f16x4_t*)((char*)obuf + (ebyte ^ ((d & 3) << 4))) = o4;
            }
        }
        __syncthreads();                    // obuf complete

        // --- coalesced store: row hr = (h*4+p) is 4 KB contiguous in dst.
        // Each inst: 64 lanes x 16B consecutive = 16 full lines.
        f16_t* dst = (s == 0) ? q : (s == 1) ? k : v;
        const int hr  = tid >> 5;           // 0..7  (h = hr>>2, p = hr&3)
        const int l32 = tid & 31;
        f16_t* drow = dst + ((size_t)((b * HH + (hr >> 2)) * PP)
                             + pt * 4 + (hr & 3)) * EE;
#pragma unroll
        for (int j = 0; j < 8; ++j) {
            const int d  = j * 8 + (l32 >> 2);
            const int tb = (l32 & 3) * 16;  // byte offset of 8-f16 t-chunk
            const f16x8_t t8 = *(const f16x8_t*)((char*)obuf
                                + (size_t)(hr * 64 + d) * 64
                                + (tb ^ ((d & 3) << 4)));
            *(f16x8_t*)((char*)drow + j * 512 + l32 * 16) = t8;
        }
        __syncthreads();                    // obuf reads done before next DMA
    }
}

// ---------------------------------------------------------------------------
// Kernel 2: transpose v [bh][p][e] -> vt [bh][e][p] (64x64 LDS tiles).
// 16 B/lane global on BOTH sides; LDS side is scalar u16 ops (cheap).
// ---------------------------------------------------------------------------
__global__ __launch_bounds__(256) void vpose_kernel(const f16_t* __restrict__ v,
                                                    f16_t* __restrict__ vt)
{
    __shared__ unsigned short lds[64][65];
    const int bh   = blockIdx.y;
    const int tile = blockIdx.x;
    const int e0 = (tile & 31) * 64;
    const int p0 = (tile >> 5) * 64;
    const int tid = threadIdx.x;
    const int rw  = tid >> 3;          // 0..31
    const int c8  = (tid & 7) * 8;     // 0..56
    const f16_t* vb  = v  + (size_t)bh * PP * EE;
    f16_t*       vtb = vt + (size_t)bh * EE * PP;
#pragma unroll
    for (int half = 0; half < 2; ++half) {
        const int p = rw + half * 32;
        const f16x8_t t = *(const f16x8_t*)(vb + (size_t)(p0 + p) * EE + e0 + c8);
#pragma unroll
        for (int j = 0; j < 8; ++j)
            lds[p][c8 + j] = __builtin_bit_cast(unsigned short, (_Float16)t[j]);
    }
    __syncthreads();
#pragma unroll
    for (int half = 0; half < 2; ++half) {
        const int e = rw + half * 32;
        f16x8_t t;
#pragma unroll
        for (int j = 0; j < 8; ++j)
            t[j] = __builtin_bit_cast(_Float16, lds[c8 + j][e]);
        *(f16x8_t*)(vtb + (size_t)(e0 + e) * PP + p0 + c8) = t;
    }
}

// ---------------------------------------------------------------------------
// Kernel 3: S = SCALE * Q @ K^T per (b,h). M=N=512, K=2048.
// grid 512 blocks 1D: bh = id&31 (same bh -> same XCD), tile = id>>5.
// S-writes are full 64B lines per quad-row (col base 64B-aligned).
// ---------------------------------------------------------------------------
__global__ __launch_bounds__(256) void qk_kernel(const f16_t* __restrict__ q,
                                                 const f16_t* __restrict__ k,
                                                 float* __restrict__ S)
{
    __shared__ f16_t As[128 * 32];
    __shared__ f16_t Bs[128 * 32];
    const int id = blockIdx.x;
    const int bh = id & 31;
    const int tile = id >> 5;               // 0..15
    const int mt = tile & 3, nt = tile >> 2;
    const int tid  = threadIdx.x;
    const int lane = tid & 63;
    const int wave = tid >> 6;
    const int wm = wave & 1, wn = wave >> 1;
    const int quad = lane >> 4, l16 = lane & 15;

    f32x4_t acc[4][4];
#pragma unroll
    for (int i = 0; i < 4; ++i)
#pragma unroll
        for (int j = 0; j < 4; ++j) acc[i][j] = (f32x4_t){0.f, 0.f, 0.f, 0.f};

    const f16_t* qb = q + (size_t)bh * PP * EE;
    const f16_t* kb = k + (size_t)bh * PP * EE;
    gemm_lds_bt(qb, EE, kb, EE, EE, mt * 128, nt * 128, As, Bs, acc);

    float* Sb = S + (size_t)bh * PP * PP;
#pragma unroll
    for (int mi = 0; mi < 4; ++mi)
#pragma unroll
        for (int r = 0; r < 4; ++r) {
            const int row = mt * 128 + wm * 64 + mi * 16 + quad * 4 + r;
#pragma unroll
            for (int ni = 0; ni < 4; ++ni) {
                const int col = nt * 128 + wn * 64 + ni * 16 + l16;
                Sb[(size_t)row * PP + col] = acc[mi][ni][r] * SCALE;
            }
        }
}

// ---------------------------------------------------------------------------
// Kernel 4: row softmax over S, writing normalized P as fp16 overlaid into
// S's storage (row pitch 1024 fp16 = 2048 B). One wave per row.
// ---------------------------------------------------------------------------
__global__ __launch_bounds__(256) void softmax_kernel(float* __restrict__ S)
{
    const int tid  = threadIdx.x;
    const int wave = tid >> 6;
    const int lane = tid & 63;
    const int row  = blockIdx.x * 4 + wave;
    float* rp = S + (size_t)row * PP;

    const float4 a = *(const float4*)(rp + lane * 8);
    const float4 b = *(const float4*)(rp + lane * 8 + 4);

    float m = fmaxf(fmaxf(fmaxf(a.x, a.y), fmaxf(a.z, a.w)),
                    fmaxf(fmaxf(b.x, b.y), fmaxf(b.z, b.w)));
#pragma unroll
    for (int off = 1; off < 64; off <<= 1) m = fmaxf(m, __shfl_xor(m, off, 64));

    float e[8];
    e[0] = expf(a.x - m); e[1] = expf(a.y - m);
    e[2] = expf(a.z - m); e[3] = expf(a.w - m);
    e[4] = expf(b.x - m); e[5] = expf(b.y - m);
    e[6] = expf(b.z - m); e[7] = expf(b.w - m);

    float sum = e[0] + e[1] + e[2] + e[3] + e[4] + e[5] + e[6] + e[7];
#pragma unroll
    for (int off = 1; off < 64; off <<= 1) sum += __shfl_xor(sum, off, 64);
    const float inv = 1.0f / sum;

    __syncthreads();   // order the fp16 stores after all float loads

    f16_t* prow = (f16_t*)rp;
    f16x8_t o;
#pragma unroll
    for (int j = 0; j < 8; ++j) o[j] = (_Float16)(e[j] * inv);
    *(f16x8_t*)(prow + lane * 8) = o;
}

// ---------------------------------------------------------------------------
// Kernel 5: O = P @ V per (b,h) -> out fp32 (b,c,p,t) (operand-swapped).
// A = vt [e][p] (M = e = 2048), Bt = P (N = p = 512), K = 512.
// D[row=e][col=p]: r advances along t -> one float4 16B store per (mi,ni);
// each inst = 16 complete 64B lines (quads fill the 4 t-chunks).
// grid 2048 blocks 1D: bh = id&31, tile = id>>5 (nt = tile&3, mt = tile>>2).
// ---------------------------------------------------------------------------
__global__ __launch_bounds__(256) void pv_kernel(const f16_t* __restrict__ Pm,
                                                 const f16_t* __restrict__ vt,
                                                 float* __restrict__ out)
{
    __shared__ f16_t As[128 * 32];
    __shared__ f16_t Bs[128 * 32];
    const int id = blockIdx.x;
    const int bh = id & 31;
    const int tile = id >> 5;               // 0..63
    const int nt = tile & 3, mt = tile >> 2;
    const int tid  = threadIdx.x;
    const int lane = tid & 63;
    const int wave = tid >> 6;
    const int wm = wave & 1, wn = wave >> 1;
    const int quad = lane >> 4, l16 = lane & 15;

    f32x4_t acc[4][4];                      // [mi: e tiles][ni: p tiles]
#pragma unroll
    for (int i = 0; i < 4; ++i)
#pragma unroll
        for (int j = 0; j < 4; ++j) acc[i][j] = (f32x4_t){0.f, 0.f, 0.f, 0.f};

    const f16_t* Pb  = Pm + (size_t)bh * PP * 1024;
    const f16_t* vtb = vt + (size_t)bh * EE * PP;
    gemm_lds_bt(vtb, PP, Pb, 1024, PP, mt * 128, nt * 128, As, Bs, acc);

    const int b = bh >> 1, h = bh & 1;
#pragma unroll
    for (int mi = 0; mi < 4; ++mi) {
        const int e0 = mt * 128 + wm * 64 + mi * 16 + quad * 4;   // r = 0..3
        const int d  = e0 >> 5;
        const int t0 = e0 & 31;             // multiple of 4 -> 16B aligned
#pragma unroll
        for (int ni = 0; ni < 4; ++ni) {
            const int p = nt * 128 + wn * 64 + ni * 16 + l16;
            *(f32x4_t*)(out + ((size_t)(b * CC + h * DD + d) * PP + p) * TT + t0)
                = acc[mi][ni];
        }
    }
}

// ---------------------------------------------------------------------------
// Workspace layout (bytes):
//   [0,   64M)  q   fp16 [b][h][p][e]
//   [64M, 128M) k   fp16 [b][h][p][e]
//   [128M,192M) v   fp16 [b][h][p][e]
//   [192M,256M) vt  fp16 [b][h][e][p]
//   [256M,288M) S   fp32 [bh][i][j]  (P fp16 overlaid, row pitch 1024 elems)
//   Wh fp16 [384][128] parked at 256M (S region) -- consumed by proj before
//   qk_kernel overwrites it with S.
// ---------------------------------------------------------------------------
extern "C" void kernel_launch(void* const* d_in, const int* in_sizes, int n_in,
                              void* d_out, int out_size, void* d_ws, size_t ws_size,
                              hipStream_t stream)
{
    const float* x    = (const float*)d_in[0];
    const float* W    = (const float*)d_in[1];
    const float* bias = (const float*)d_in[2];
    float* out = (float*)d_out;

    char* ws = (char*)d_ws;
    const size_t MiB = 1024ull * 1024ull;
    f16_t* q  = (f16_t*)(ws);
    f16_t* k  = (f16_t*)(ws + 64 * MiB);
    f16_t* v  = (f16_t*)(ws + 128 * MiB);
    f16_t* vt = (f16_t*)(ws + 192 * MiB);
    float* S  = (float*)(ws + 256 * MiB);
    f16_t* Wh = (f16_t*)(ws + 256 * MiB);   // overlaid with S (safe: see above)

    wcvt_kernel<<<dim3(48), dim3(256), 0, stream>>>(W, Wh);
    proj_kernel<<<dim3(128, 16), dim3(256), 0, stream>>>(x, Wh, bias, q, k, v);
    vpose_kernel<<<dim3(256, 32), dim3(256), 0, stream>>>(v, vt);
    qk_kernel<<<dim3(512), dim3(256), 0, stream>>>(q, k, S);
    softmax_kernel<<<dim3(4096), dim3(256), 0, stream>>>(S);
    pv_kernel<<<dim3(2048), dim3(256), 0, stream>>>((const f16_t*)S, vt, out);
}

// Round 8
// 494.721 us; speedup vs baseline: 1.1175x; 1.0077x over previous
//
#include <hip/hip_runtime.h>

// Problem constants
#define BB 16
#define CC 128
#define PP 512
#define TT 32
#define HH 2
#define DD 64
#define EE 2048        // D*T
#define NPIX 16384     // P*T
#define SCALE 0.125f   // D^-0.5

typedef _Float16 f16_t;
typedef _Float16 f16x8_t __attribute__((ext_vector_type(8)));
typedef _Float16 f16x4_t __attribute__((ext_vector_type(4)));
typedef float    f32x4_t __attribute__((ext_vector_type(4)));

#define AS_GLOBAL __attribute__((address_space(1)))
#define AS_LDS    __attribute__((address_space(3)))

// Async global->LDS DMA, 16 B per lane. LDS dest is wave-uniform base;
// lane i's 16 B land at base + i*16 (HW-defined, m104/m108). Global source
// address is PER-LANE (m173) -- scatter-gather on the read side is legal.
__device__ __forceinline__ void async_ld16(const void* g, void* l) {
    __builtin_amdgcn_global_load_lds((const AS_GLOBAL void*)g,
                                     (AS_LDS void*)l, 16, 0, 0);
}

// ---------------------------------------------------------------------------
// LDS-staged GEMM core (m97 structure, single-buffer BK=32): C = A @ Bt^T.
// 256 threads / 4 waves; wave = 64x64 (4x4 of 16x16x32 MFMA).
// LDS tile: chunk-major, slot s = chunk*128 + row holds row's
// fp16[chunk*8..chunk*8+8) -- contiguous in lane order for global_load_lds
// and phase-minimal on the 64-lane ds_read_b128.
// MFMA lane mapping (HW-verified): A[m=lane&15][k=quad*8+j],
// B[k=quad*8+j][n=lane&15], D[row=quad*4+reg][col=lane&15].
// ---------------------------------------------------------------------------
__device__ __forceinline__ void gemm_lds_bt(const f16_t* __restrict__ A, int lda,
                                            const f16_t* __restrict__ Bt, int ldb,
                                            int K, int m0, int n0,
                                            f16_t* As, f16_t* Bs,
                                            f32x4_t acc[4][4])
{
    const int tid  = threadIdx.x;
    const int lane = tid & 63;
    const int wave = tid >> 6;
    const int wm = wave & 1, wn = wave >> 1;
    const int quad = lane >> 4, l16 = lane & 15;

    const f16_t* gA0 = A  + (size_t)(m0 + lane)      * lda + wave * 8;
    const f16_t* gA1 = A  + (size_t)(m0 + 64 + lane) * lda + wave * 8;
    const f16_t* gB0 = Bt + (size_t)(n0 + lane)      * ldb + wave * 8;
    const f16_t* gB1 = Bt + (size_t)(n0 + 64 + lane) * ldb + wave * 8;
    f16_t* lA0 = As + (size_t)(wave * 128)      * 8;
    f16_t* lA1 = As + (size_t)(wave * 128 + 64) * 8;
    f16_t* lB0 = Bs + (size_t)(wave * 128)      * 8;
    f16_t* lB1 = Bs + (size_t)(wave * 128 + 64) * 8;

    const int ar = wm * 64 + l16;
    const int br = wn * 64 + l16;

    for (int k0 = 0; k0 < K; k0 += 32) {
        if (k0) __syncthreads();            // prior iter's LDS reads done
        async_ld16(gA0 + k0, lA0);
        async_ld16(gA1 + k0, lA1);
        async_ld16(gB0 + k0, lB0);
        async_ld16(gB1 + k0, lB1);
        __syncthreads();                    // vmcnt(0) drain + barrier

        f16x8_t af[4], bf[4];
#pragma unroll
        for (int mi = 0; mi < 4; ++mi)
            af[mi] = *(const f16x8_t*)(As + (size_t)(quad * 128 + ar + mi * 16) * 8);
#pragma unroll
        for (int ni = 0; ni < 4; ++ni)
            bf[ni] = *(const f16x8_t*)(Bs + (size_t)(quad * 128 + br + ni * 16) * 8);
#pragma unroll
        for (int mi = 0; mi < 4; ++mi)
#pragma unroll
            for (int ni = 0; ni < 4; ++ni)
                acc[mi][ni] = __builtin_amdgcn_mfma_f32_16x16x32_f16(
                    af[mi], bf[ni], acc[mi][ni], 0, 0, 0);
    }
}

// ---------------------------------------------------------------------------
// Kernel 0: W fp32 -> fp16 (one-time, 49152 elems). Wh parked in the S
// region of the workspace (S isn't written until qk_kernel, after proj).
// ---------------------------------------------------------------------------
__global__ __launch_bounds__(256) void wcvt_kernel(const float* __restrict__ W,
                                                   f16_t* __restrict__ Wh)
{
    const int i = (blockIdx.x * 256 + threadIdx.x) * 4;
    const float4 wv = *(const float4*)(W + i);
    f16x4_t t;
    t[0] = (_Float16)wv.x; t[1] = (_Float16)wv.y;
    t[2] = (_Float16)wv.z; t[3] = (_Float16)wv.w;
    *(f16x4_t*)(Wh + i) = t;
}

// ---------------------------------------------------------------------------
// Kernel 1: QKV projection, v6 (occupancy: 2 -> 3 blocks/CU).
// Round-7 post-mortem: v5 = 119us with MfmaUtil 8 / VALU 12 / HBM 36% /
// Occ 19.4 -- NOTHING busy = latency-bound, insufficient TLP. v5's 64 KB
// LDS hard-capped residency at 2 blocks/CU while regs (104+64acc=168)
// allow 3. Round-4's occupancy attempt failed because it doubled per-block
// W traffic; this version changes NO per-block traffic:
//  - wbuf 32 -> 16 KB: W slice staged in two K-halves (ch 0-7, 8-15) with
//    a restage barrier mid-K-loop (same total DMA insts).
//  - obuf round-trip dropped (v5 proved store coalescing ~4us); back to
//    v4's direct packed f16x4 stores (bit-identical math).
//  - LDS 48 KB + __launch_bounds__(256,3) -> 3 blocks/CU.
// grid (128, 16), block 256.
// ---------------------------------------------------------------------------
__global__ __launch_bounds__(256, 3) void proj_kernel(const float* __restrict__ x,
                                                      const f16_t* __restrict__ Wh,
                                                      const float* __restrict__ bias,
                                                      f16_t* __restrict__ q,
                                                      f16_t* __restrict__ k,
                                                      f16_t* __restrict__ v)
{
    __shared__ f16_t xs[CC * 128];          // swizzled [pix][c] fp16, 32 KB
    __shared__ f16_t wbuf[8 * 128 * 8];     // chunk-major W half-slice, 16 KB
    const int b    = blockIdx.y;
    const int pt   = blockIdx.x;
    const int tid  = threadIdx.x;
    const int lane = tid & 63;
    const int wave = tid >> 6;
    const int wm   = wave & 1, wn = wave >> 1;   // wm: pix half, wn: o half
    const int quad = lane >> 4, l16 = lane & 15;
    const int pixb = pt * 128;

    const float* xb = x + (size_t)b * CC * NPIX;

    // Stage x tile as fp16 transposed [pix][c], XOR-swizzled.
    // Loads coalesced (lanes = consecutive pix, 256B/inst); each lane packs
    // 8 consecutive c for its pixel -> 1 swizzled ds_write_b128.
#pragma unroll 2
    for (int r = 0; r < 8; ++r) {
        const int u  = r * 4 + wave;        // 0..31
        const int c0 = (u >> 1) * 8;        // 0,8,...,120
        const int pl = (u & 1) * 64 + lane; // 0..127
        const float* g = xb + (size_t)c0 * NPIX + pixb + pl;
        float vv[8];
#pragma unroll
        for (int j = 0; j < 8; ++j) vv[j] = g[(size_t)j * NPIX];
        f16x8_t t;
#pragma unroll
        for (int j = 0; j < 8; ++j) t[j] = (_Float16)vv[j];
        *(f16x8_t*)((char*)xs + pl * 256 + ((c0 * 2) ^ ((pl & 15) << 4))) = t;
    }
    // First barrier inside the s/khalf loop covers xs completion.

    for (int s = 0; s < 3; ++s) {
        f32x4_t acc[4][4];                  // [mi: pix tiles][ni: o tiles]
#pragma unroll
        for (int i = 0; i < 4; ++i)
#pragma unroll
            for (int j = 0; j < 4; ++j) acc[i][j] = (f32x4_t){0.f, 0.f, 0.f, 0.f};

#pragma unroll
        for (int khalf = 0; khalf < 2; ++khalf) {
            __syncthreads();                // prior wbuf reads (or xs stage) done
            // Stage W half-slice: slot ch*128+o holds
            // Wh[s*128+o][(khalf*8+ch)*8 .. +8). 16 insts/block, per-lane src.
#pragma unroll
            for (int i = 0; i < 4; ++i) {
                const int idx = wave * 4 + i;   // 0..15
                const int ch  = idx >> 1;       // 0..7
                const int oh  = (idx & 1) * 64; // 0 / 64
                async_ld16(Wh + (size_t)(s * 128 + oh + lane) * CC
                              + (khalf * 8 + ch) * 8,
                           wbuf + ((size_t)ch * 128 + oh) * 8);
            }
            __syncthreads();                // wbuf ready

#pragma unroll
            for (int kk = 0; kk < 2; ++kk) {
                const int k0  = khalf * 64 + kk * 32;
                const int kq  = k0 + quad * 8;
                const int chq = kk * 4 + quad;         // local chunk in wbuf
                f16x8_t xf[4], wf[4];
#pragma unroll
                for (int mi = 0; mi < 4; ++mi) {       // A = x[pix][c]
                    const int pl = wm * 64 + mi * 16 + l16;
                    xf[mi] = *(const f16x8_t*)((char*)xs + pl * 256 +
                                               ((kq * 2) ^ ((pl & 15) << 4)));
                }
#pragma unroll
                for (int ni = 0; ni < 4; ++ni) {       // B = W[o][c] via LDS
                    const int ol = wn * 64 + ni * 16 + l16;
                    wf[ni] = *(const f16x8_t*)(wbuf + ((size_t)chq * 128 + ol) * 8);
                }
#pragma unroll
                for (int mi = 0; mi < 4; ++mi)
#pragma unroll
                    for (int ni = 0; ni < 4; ++ni)
                        acc[mi][ni] = __builtin_amdgcn_mfma_f32_16x16x32_f16(
                            xf[mi], wf[ni], acc[mi][ni], 0, 0, 0);
            }
        }

        // bias per (s, ni): o depends on l16 -> per-lane scalar load.
        float bv[4];
#pragma unroll
        for (int ni = 0; ni < 4; ++ni)
            bv[ni] = bias[s * 128 + wn * 64 + ni * 16 + l16];

        // Direct packed stores (v4 pattern): D[row=pix][col=o]; r advances
        // along t (contiguous) -> one 8B f16x4 store per (mi,ni).
        f16_t* dst = (s == 0) ? q : (s == 1) ? k : v;
        const int h = wn;                   // o_local>>6
#pragma unroll
        for (int mi = 0; mi < 4; ++mi) {
            const int pix0 = pixb + wm * 64 + mi * 16 + quad * 4;  // r = 0..3
            const int p  = pix0 >> 5;
            const int t0 = pix0 & 31;       // multiple of 4 -> 8B aligned
#pragma unroll
            for (int ni = 0; ni < 4; ++ni) {
                const int d = ni * 16 + l16;
                f16x4_t o4;
#pragma unroll
                for (int r = 0; r < 4; ++r)
                    o4[r] = (_Float16)(acc[mi][ni][r] + bv[ni]);
                *(f16x4_t*)(dst + ((size_t)((b * HH + h) * PP + p)) * EE
                                + d * TT + t0) = o4;
            }
        }
    }
}

// ---------------------------------------------------------------------------
// Kernel 2: transpose v [bh][p][e] -> vt [bh][e][p] (64x64 LDS tiles).
// 16 B/lane global on BOTH sides; LDS side is scalar u16 ops (cheap).
// ---------------------------------------------------------------------------
__global__ __launch_bounds__(256) void vpose_kernel(const f16_t* __restrict__ v,
                                                    f16_t* __restrict__ vt)
{
    __shared__ unsigned short lds[64][65];
    const int bh   = blockIdx.y;
    const int tile = blockIdx.x;
    const int e0 = (tile & 31) * 64;
    const int p0 = (tile >> 5) * 64;
    const int tid = threadIdx.x;
    const int rw  = tid >> 3;          // 0..31
    const int c8  = (tid & 7) * 8;     // 0..56
    const f16_t* vb  = v  + (size_t)bh * PP * EE;
    f16_t*       vtb = vt + (size_t)bh * EE * PP;
#pragma unroll
    for (int half = 0; half < 2; ++half) {
        const int p = rw + half * 32;
        const f16x8_t t = *(const f16x8_t*)(vb + (size_t)(p0 + p) * EE + e0 + c8);
#pragma unroll
        for (int j = 0; j < 8; ++j)
            lds[p][c8 + j] = __builtin_bit_cast(unsigned short, (_Float16)t[j]);
    }
    __syncthreads();
#pragma unroll
    for (int half = 0; half < 2; ++half) {
        const int e = rw + half * 32;
        f16x8_t t;
#pragma unroll
        for (int j = 0; j < 8; ++j)
            t[j] = __builtin_bit_cast(_Float16, lds[c8 + j][e]);
        *(f16x8_t*)(vtb + (size_t)(e0 + e) * PP + p0 + c8) = t;
    }
}

// ---------------------------------------------------------------------------
// Kernel 3: S = SCALE * Q @ K^T per (b,h). M=N=512, K=2048.
// grid 512 blocks 1D: bh = id&31 (same bh -> same XCD), tile = id>>5.
// S-writes are full 64B lines per quad-row (col base 64B-aligned).
// ---------------------------------------------------------------------------
__global__ __launch_bounds__(256) void qk_kernel(const f16_t* __restrict__ q,
                                                 const f16_t* __restrict__ k,
                                                 float* __restrict__ S)
{
    __shared__ f16_t As[128 * 32];
    __shared__ f16_t Bs[128 * 32];
    const int id = blockIdx.x;
    const int bh = id & 31;
    const int tile = id >> 5;               // 0..15
    const int mt = tile & 3, nt = tile >> 2;
    const int tid  = threadIdx.x;
    const int lane = tid & 63;
    const int wave = tid >> 6;
    const int wm = wave & 1, wn = wave >> 1;
    const int quad = lane >> 4, l16 = lane & 15;

    f32x4_t acc[4][4];
#pragma unroll
    for (int i = 0; i < 4; ++i)
#pragma unroll
        for (int j = 0; j < 4; ++j) acc[i][j] = (f32x4_t){0.f, 0.f, 0.f, 0.f};

    const f16_t* qb = q + (size_t)bh * PP * EE;
    const f16_t* kb = k + (size_t)bh * PP * EE;
    gemm_lds_bt(qb, EE, kb, EE, EE, mt * 128, nt * 128, As, Bs, acc);

    float* Sb = S + (size_t)bh * PP * PP;
#pragma unroll
    for (int mi = 0; mi < 4; ++mi)
#pragma unroll
        for (int r = 0; r < 4; ++r) {
            const int row = mt * 128 + wm * 64 + mi * 16 + quad * 4 + r;
#pragma unroll
            for (int ni = 0; ni < 4; ++ni) {
                const int col = nt * 128 + wn * 64 + ni * 16 + l16;
                Sb[(size_t)row * PP + col] = acc[mi][ni][r] * SCALE;
            }
        }
}

// ---------------------------------------------------------------------------
// Kernel 4: row softmax over S, writing normalized P as fp16 overlaid into
// S's storage (row pitch 1024 fp16 = 2048 B). One wave per row.
// ---------------------------------------------------------------------------
__global__ __launch_bounds__(256) void softmax_kernel(float* __restrict__ S)
{
    const int tid  = threadIdx.x;
    const int wave = tid >> 6;
    const int lane = tid & 63;
    const int row  = blockIdx.x * 4 + wave;
    float* rp = S + (size_t)row * PP;

    const float4 a = *(const float4*)(rp + lane * 8);
    const float4 b = *(const float4*)(rp + lane * 8 + 4);

    float m = fmaxf(fmaxf(fmaxf(a.x, a.y), fmaxf(a.z, a.w)),
                    fmaxf(fmaxf(b.x, b.y), fmaxf(b.z, b.w)));
#pragma unroll
    for (int off = 1; off < 64; off <<= 1) m = fmaxf(m, __shfl_xor(m, off, 64));

    float e[8];
    e[0] = expf(a.x - m); e[1] = expf(a.y - m);
    e[2] = expf(a.z - m); e[3] = expf(a.w - m);
    e[4] = expf(b.x - m); e[5] = expf(b.y - m);
    e[6] = expf(b.z - m); e[7] = expf(b.w - m);

    float sum = e[0] + e[1] + e[2] + e[3] + e[4] + e[5] + e[6] + e[7];
#pragma unroll
    for (int off = 1; off < 64; off <<= 1) sum += __shfl_xor(sum, off, 64);
    const float inv = 1.0f / sum;

    __syncthreads();   // order the fp16 stores after all float loads

    f16_t* prow = (f16_t*)rp;
    f16x8_t o;
#pragma unroll
    for (int j = 0; j < 8; ++j) o[j] = (_Float16)(e[j] * inv);
    *(f16x8_t*)(prow + lane * 8) = o;
}

// ---------------------------------------------------------------------------
// Kernel 5: O = P @ V per (b,h) -> out fp32 (b,c,p,t) (operand-swapped).
// A = vt [e][p] (M = e = 2048), Bt = P (N = p = 512), K = 512.
// D[row=e][col=p]: r advances along t -> one float4 16B store per (mi,ni);
// each inst = 16 complete 64B lines (quads fill the 4 t-chunks).
// grid 2048 blocks 1D: bh = id&31, tile = id>>5 (nt = tile&3, mt = tile>>2).
// ---------------------------------------------------------------------------
__global__ __launch_bounds__(256) void pv_kernel(const f16_t* __restrict__ Pm,
                                                 const f16_t* __restrict__ vt,
                                                 float* __restrict__ out)
{
    __shared__ f16_t As[128 * 32];
    __shared__ f16_t Bs[128 * 32];
    const int id = blockIdx.x;
    const int bh = id & 31;
    const int tile = id >> 5;               // 0..63
    const int nt = tile & 3, mt = tile >> 2;
    const int tid  = threadIdx.x;
    const int lane = tid & 63;
    const int wave = tid >> 6;
    const int wm = wave & 1, wn = wave >> 1;
    const int quad = lane >> 4, l16 = lane & 15;

    f32x4_t acc[4][4];                      // [mi: e tiles][ni: p tiles]
#pragma unroll
    for (int i = 0; i < 4; ++i)
#pragma unroll
        for (int j = 0; j < 4; ++j) acc[i][j] = (f32x4_t){0.f, 0.f, 0.f, 0.f};

    const f16_t* Pb  = Pm + (size_t)bh * PP * 1024;
    const f16_t* vtb = vt + (size_t)bh * EE * PP;
    gemm_lds_bt(vtb, PP, Pb, 1024, PP, mt * 128, nt * 128, As, Bs, acc);

    const int b = bh >> 1, h = bh & 1;
#pragma unroll
    for (int mi = 0; mi < 4; ++mi) {
        const int e0 = mt * 128 + wm * 64 + mi * 16 + quad * 4;   // r = 0..3
        const int d  = e0 >> 5;
        const int t0 = e0 & 31;             // multiple of 4 -> 16B aligned
#pragma unroll
        for (int ni = 0; ni < 4; ++ni) {
            const int p = nt * 128 + wn * 64 + ni * 16 + l16;
            *(f32x4_t*)(out + ((size_t)(b * CC + h * DD + d) * PP + p) * TT + t0)
                = acc[mi][ni];
        }
    }
}

// ---------------------------------------------------------------------------
// Workspace layout (bytes):
//   [0,   64M)  q   fp16 [b][h][p][e]
//   [64M, 128M) k   fp16 [b][h][p][e]
//   [128M,192M) v   fp16 [b][h][p][e]
//   [192M,256M) vt  fp16 [b][h][e][p]
//   [256M,288M) S   fp32 [bh][i][j]  (P fp16 overlaid, row pitch 1024 elems)
//   Wh fp16 [384][128] parked at 256M (S region) -- consumed by proj before
//   qk_kernel overwrites it with S.
// ---------------------------------------------------------------------------
extern "C" void kernel_launch(void* const* d_in, const int* in_sizes, int n_in,
                              void* d_out, int out_size, void* d_ws, size_t ws_size,
                              hipStream_t stream)
{
    const float* x    = (const float*)d_in[0];
    const float* W    = (const float*)d_in[1];
    const float* bias = (const float*)d_in[2];
    float* out = (float*)d_out;

    char* ws = (char*)d_ws;
    const size_t MiB = 1024ull * 1024ull;
    f16_t* q  = (f16_t*)(ws);
    f16_t* k  = (f16_t*)(ws + 64 * MiB);
    f16_t* v  = (f16_t*)(ws + 128 * MiB);
    f16_t* vt = (f16_t*)(ws + 192 * MiB);
    float* S  = (float*)(ws + 256 * MiB);
    f16_t* Wh = (f16_t*)(ws + 256 * MiB);   // overlaid with S (safe: see above)

    wcvt_kernel<<<dim3(48), dim3(256), 0, stream>>>(W, Wh);
    proj_kernel<<<dim3(128, 16), dim3(256), 0, stream>>>(x, Wh, bias, q, k, v);
    vpose_kernel<<<dim3(256, 32), dim3(256), 0, stream>>>(v, vt);
    qk_kernel<<<dim3(512), dim3(256), 0, stream>>>(q, k, S);
    softmax_kernel<<<dim3(4096), dim3(256), 0, stream>>>(S);
    pv_kernel<<<dim3(2048), dim3(256), 0, stream>>>((const f16_t*)S, vt, out);
}

// Round 9
// 492.343 us; speedup vs baseline: 1.1229x; 1.0048x over previous
//
#include <hip/hip_runtime.h>

// Problem constants
#define BB 16
#define CC 128
#define PP 512
#define TT 32
#define HH 2
#define DD 64
#define EE 2048        // D*T
#define NPIX 16384     // P*T
#define SCALE 0.125f   // D^-0.5

typedef _Float16 f16_t;
typedef _Float16 f16x8_t __attribute__((ext_vector_type(8)));
typedef _Float16 f16x4_t __attribute__((ext_vector_type(4)));
typedef float    f32x4_t __attribute__((ext_vector_type(4)));

#define AS_GLOBAL __attribute__((address_space(1)))
#define AS_LDS    __attribute__((address_space(3)))

// Async global->LDS DMA, 16 B per lane. LDS dest is wave-uniform base;
// lane i's 16 B land at base + i*16 (HW-defined, m104/m108). Global source
// address is PER-LANE (m173) -- scatter-gather on the read side is legal.
__device__ __forceinline__ void async_ld16(const void* g, void* l) {
    __builtin_amdgcn_global_load_lds((const AS_GLOBAL void*)g,
                                     (AS_LDS void*)l, 16, 0, 0);
}

// ---------------------------------------------------------------------------
// Pipelined LDS-staged GEMM core (T3+T4 minimum recipe, raw barriers +
// counted vmcnt): C(128x128) = A @ Bt^T. 256 threads / 4 waves; wave =
// 64x64 (4x4 of 16x16x32 MFMA). BK=32, DOUBLE-buffered (2x8 KB per
// matrix = 32 KB total -> 4-5 blocks/CU residency preserved).
//
// Why: round-8 PMC showed qk/pv at ~850 cy/K-step critical path where
// compute is ~180 cy -- the __syncthreads()-forced s_waitcnt vmcnt(0)
// exposes the full staging latency every step (m97-structure stall).
// Protocol per step t:
//   stage(buf^1, t+1)            // 4 global_load_lds per wave, in flight
//   s_waitcnt vmcnt(4)           // wait OWN 4 loads of buf (issued t-1);
//                                //   the 4 just-issued stay outstanding
//   s_barrier                    // => all waves' buf data complete
//   ds_read + 16 MFMA on buf
//   s_waitcnt lgkmcnt(0)         // reads drained (cheap: already done)
//   s_barrier                    // => safe to overwrite buf at t+1
// vmcnt counts complete in issue order; each wave issues exactly 4 per
// stage, so vmcnt(4) == "previous stage fully landed". Never drains to 0
// mid-loop (AITER/HK pattern). "memory" clobbers pin LDS ordering.
// LDS tile: chunk-major, slot = chunk*128 + row (contiguous in lane order
// for global_load_lds; phase-minimal ds_read_b128).
// MFMA lane mapping (HW-verified): A[m=lane&15][k=quad*8+j],
// B[k=quad*8+j][n=lane&15], D[row=quad*4+reg][col=lane&15].
// ---------------------------------------------------------------------------
__device__ __forceinline__ void gemm_lds_bt_pipe(const f16_t* __restrict__ A, int lda,
                                                 const f16_t* __restrict__ Bt, int ldb,
                                                 int K, int m0, int n0,
                                                 f16_t* As, f16_t* Bs, // each 2*128*32
                                                 f32x4_t acc[4][4])
{
    const int tid  = threadIdx.x;
    const int lane = tid & 63;
    const int wave = tid >> 6;
    const int wm = wave & 1, wn = wave >> 1;
    const int quad = lane >> 4, l16 = lane & 15;
    constexpr int TILE = 128 * 32;          // f16 per buffer per matrix

    const f16_t* gA0 = A  + (size_t)(m0 + lane)      * lda + wave * 8;
    const f16_t* gA1 = A  + (size_t)(m0 + 64 + lane) * lda + wave * 8;
    const f16_t* gB0 = Bt + (size_t)(n0 + lane)      * ldb + wave * 8;
    const f16_t* gB1 = Bt + (size_t)(n0 + 64 + lane) * ldb + wave * 8;

    const int ar = wm * 64 + l16;
    const int br = wn * 64 + l16;

    auto stage = [&](int buf, int k0) {
        f16_t* dA = As + buf * TILE;
        f16_t* dB = Bs + buf * TILE;
        async_ld16(gA0 + k0, dA + (size_t)(wave * 128)      * 8);
        async_ld16(gA1 + k0, dA + (size_t)(wave * 128 + 64) * 8);
        async_ld16(gB0 + k0, dB + (size_t)(wave * 128)      * 8);
        async_ld16(gB1 + k0, dB + (size_t)(wave * 128 + 64) * 8);
    };

    stage(0, 0);                            // prologue: fill buffer 0
    int cur = 0;
    const int nsteps = K >> 5;

    for (int t = 0; t < nsteps; ++t) {
        if (t + 1 < nsteps) {
            stage(cur ^ 1, (t + 1) << 5);   // prefetch next tile (4 insts)
            asm volatile("s_waitcnt vmcnt(4)" ::: "memory");
        } else {
            asm volatile("s_waitcnt vmcnt(0)" ::: "memory");
        }
        __builtin_amdgcn_s_barrier();       // buf[cur] complete for all waves

        const f16_t* sA = As + cur * TILE;
        const f16_t* sB = Bs + cur * TILE;
        f16x8_t af[4], bf[4];
#pragma unroll
        for (int mi = 0; mi < 4; ++mi)
            af[mi] = *(const f16x8_t*)(sA + (size_t)(quad * 128 + ar + mi * 16) * 8);
#pragma unroll
        for (int ni = 0; ni < 4; ++ni)
            bf[ni] = *(const f16x8_t*)(sB + (size_t)(quad * 128 + br + ni * 16) * 8);
#pragma unroll
        for (int mi = 0; mi < 4; ++mi)
#pragma unroll
            for (int ni = 0; ni < 4; ++ni)
                acc[mi][ni] = __builtin_amdgcn_mfma_f32_16x16x32_f16(
                    af[mi], bf[ni], acc[mi][ni], 0, 0, 0);

        asm volatile("s_waitcnt lgkmcnt(0)" ::: "memory");  // LDS reads drained
        __builtin_amdgcn_s_barrier();       // safe to overwrite buf[cur] next
        cur ^= 1;
    }
}

// ---------------------------------------------------------------------------
// Kernel 0: W fp32 -> fp16 (one-time, 49152 elems). Wh parked in the S
// region of the workspace (S isn't written until qk_kernel, after proj).
// ---------------------------------------------------------------------------
__global__ __launch_bounds__(256) void wcvt_kernel(const float* __restrict__ W,
                                                   f16_t* __restrict__ Wh)
{
    const int i = (blockIdx.x * 256 + threadIdx.x) * 4;
    const float4 wv = *(const float4*)(W + i);
    f16x4_t t;
    t[0] = (_Float16)wv.x; t[1] = (_Float16)wv.y;
    t[2] = (_Float16)wv.z; t[3] = (_Float16)wv.w;
    *(f16x4_t*)(Wh + i) = t;
}

// ---------------------------------------------------------------------------
// Kernel 1: QKV projection, v6 (unchanged from round 8; 115 us measured).
// ---------------------------------------------------------------------------
__global__ __launch_bounds__(256, 3) void proj_kernel(const float* __restrict__ x,
                                                      const f16_t* __restrict__ Wh,
                                                      const float* __restrict__ bias,
                                                      f16_t* __restrict__ q,
                                                      f16_t* __restrict__ k,
                                                      f16_t* __restrict__ v)
{
    __shared__ f16_t xs[CC * 128];          // swizzled [pix][c] fp16, 32 KB
    __shared__ f16_t wbuf[8 * 128 * 8];     // chunk-major W half-slice, 16 KB
    const int b    = blockIdx.y;
    const int pt   = blockIdx.x;
    const int tid  = threadIdx.x;
    const int lane = tid & 63;
    const int wave = tid >> 6;
    const int wm   = wave & 1, wn = wave >> 1;   // wm: pix half, wn: o half
    const int quad = lane >> 4, l16 = lane & 15;
    const int pixb = pt * 128;

    const float* xb = x + (size_t)b * CC * NPIX;

#pragma unroll 2
    for (int r = 0; r < 8; ++r) {
        const int u  = r * 4 + wave;        // 0..31
        const int c0 = (u >> 1) * 8;        // 0,8,...,120
        const int pl = (u & 1) * 64 + lane; // 0..127
        const float* g = xb + (size_t)c0 * NPIX + pixb + pl;
        float vv[8];
#pragma unroll
        for (int j = 0; j < 8; ++j) vv[j] = g[(size_t)j * NPIX];
        f16x8_t t;
#pragma unroll
        for (int j = 0; j < 8; ++j) t[j] = (_Float16)vv[j];
        *(f16x8_t*)((char*)xs + pl * 256 + ((c0 * 2) ^ ((pl & 15) << 4))) = t;
    }
    // First barrier inside the s/khalf loop covers xs completion.

    for (int s = 0; s < 3; ++s) {
        f32x4_t acc[4][4];                  // [mi: pix tiles][ni: o tiles]
#pragma unroll
        for (int i = 0; i < 4; ++i)
#pragma unroll
            for (int j = 0; j < 4; ++j) acc[i][j] = (f32x4_t){0.f, 0.f, 0.f, 0.f};

#pragma unroll
        for (int khalf = 0; khalf < 2; ++khalf) {
            __syncthreads();                // prior wbuf reads (or xs stage) done
#pragma unroll
            for (int i = 0; i < 4; ++i) {
                const int idx = wave * 4 + i;   // 0..15
                const int ch  = idx >> 1;       // 0..7
                const int oh  = (idx & 1) * 64; // 0 / 64
                async_ld16(Wh + (size_t)(s * 128 + oh + lane) * CC
                              + (khalf * 8 + ch) * 8,
                           wbuf + ((size_t)ch * 128 + oh) * 8);
            }
            __syncthreads();                // wbuf ready

#pragma unroll
            for (int kk = 0; kk < 2; ++kk) {
                const int k0  = khalf * 64 + kk * 32;
                const int kq  = k0 + quad * 8;
                const int chq = kk * 4 + quad;         // local chunk in wbuf
                f16x8_t xf[4], wf[4];
#pragma unroll
                for (int mi = 0; mi < 4; ++mi) {       // A = x[pix][c]
                    const int pl = wm * 64 + mi * 16 + l16;
                    xf[mi] = *(const f16x8_t*)((char*)xs + pl * 256 +
                                               ((kq * 2) ^ ((pl & 15) << 4)));
                }
#pragma unroll
                for (int ni = 0; ni < 4; ++ni) {       // B = W[o][c] via LDS
                    const int ol = wn * 64 + ni * 16 + l16;
                    wf[ni] = *(const f16x8_t*)(wbuf + ((size_t)chq * 128 + ol) * 8);
                }
#pragma unroll
                for (int mi = 0; mi < 4; ++mi)
#pragma unroll
                    for (int ni = 0; ni < 4; ++ni)
                        acc[mi][ni] = __builtin_amdgcn_mfma_f32_16x16x32_f16(
                            xf[mi], wf[ni], acc[mi][ni], 0, 0, 0);
            }
        }

        float bv[4];
#pragma unroll
        for (int ni = 0; ni < 4; ++ni)
            bv[ni] = bias[s * 128 + wn * 64 + ni * 16 + l16];

        f16_t* dst = (s == 0) ? q : (s == 1) ? k : v;
        const int h = wn;                   // o_local>>6
#pragma unroll
        for (int mi = 0; mi < 4; ++mi) {
            const int pix0 = pixb + wm * 64 + mi * 16 + quad * 4;  // r = 0..3
            const int p  = pix0 >> 5;
            const int t0 = pix0 & 31;       // multiple of 4 -> 8B aligned
#pragma unroll
            for (int ni = 0; ni < 4; ++ni) {
                const int d = ni * 16 + l16;
                f16x4_t o4;
#pragma unroll
                for (int r = 0; r < 4; ++r)
                    o4[r] = (_Float16)(acc[mi][ni][r] + bv[ni]);
                *(f16x4_t*)(dst + ((size_t)((b * HH + h) * PP + p)) * EE
                                + d * TT + t0) = o4;
            }
        }
    }
}

// ---------------------------------------------------------------------------
// Kernel 2: transpose v [bh][p][e] -> vt [bh][e][p] (64x64 LDS tiles).
// 16 B/lane global on BOTH sides; LDS side is scalar u16 ops (cheap).
// ---------------------------------------------------------------------------
__global__ __launch_bounds__(256) void vpose_kernel(const f16_t* __restrict__ v,
                                                    f16_t* __restrict__ vt)
{
    __shared__ unsigned short lds[64][65];
    const int bh   = blockIdx.y;
    const int tile = blockIdx.x;
    const int e0 = (tile & 31) * 64;
    const int p0 = (tile >> 5) * 64;
    const int tid = threadIdx.x;
    const int rw  = tid >> 3;          // 0..31
    const int c8  = (tid & 7) * 8;     // 0..56
    const f16_t* vb  = v  + (size_t)bh * PP * EE;
    f16_t*       vtb = vt + (size_t)bh * EE * PP;
#pragma unroll
    for (int half = 0; half < 2; ++half) {
        const int p = rw + half * 32;
        const f16x8_t t = *(const f16x8_t*)(vb + (size_t)(p0 + p) * EE + e0 + c8);
#pragma unroll
        for (int j = 0; j < 8; ++j)
            lds[p][c8 + j] = __builtin_bit_cast(unsigned short, (_Float16)t[j]);
    }
    __syncthreads();
#pragma unroll
    for (int half = 0; half < 2; ++half) {
        const int e = rw + half * 32;
        f16x8_t t;
#pragma unroll
        for (int j = 0; j < 8; ++j)
            t[j] = __builtin_bit_cast(_Float16, lds[c8 + j][e]);
        *(f16x8_t*)(vtb + (size_t)(e0 + e) * PP + p0 + c8) = t;
    }
}

// ---------------------------------------------------------------------------
// Kernel 3: S = SCALE * Q @ K^T per (b,h). M=N=512, K=2048 (64 pipelined
// steps). grid 512 blocks 1D: bh = id&31, tile = id>>5. LDS 32 KB.
// ---------------------------------------------------------------------------
__global__ __launch_bounds__(256) void qk_kernel(const f16_t* __restrict__ q,
                                                 const f16_t* __restrict__ k,
                                                 float* __restrict__ S)
{
    __shared__ f16_t As[2 * 128 * 32];
    __shared__ f16_t Bs[2 * 128 * 32];
    const int id = blockIdx.x;
    const int bh = id & 31;
    const int tile = id >> 5;               // 0..15
    const int mt = tile & 3, nt = tile >> 2;
    const int tid  = threadIdx.x;
    const int lane = tid & 63;
    const int wave = tid >> 6;
    const int wm = wave & 1, wn = wave >> 1;
    const int quad = lane >> 4, l16 = lane & 15;

    f32x4_t acc[4][4];
#pragma unroll
    for (int i = 0; i < 4; ++i)
#pragma unroll
        for (int j = 0; j < 4; ++j) acc[i][j] = (f32x4_t){0.f, 0.f, 0.f, 0.f};

    const f16_t* qb = q + (size_t)bh * PP * EE;
    const f16_t* kb = k + (size_t)bh * PP * EE;
    gemm_lds_bt_pipe(qb, EE, kb, EE, EE, mt * 128, nt * 128, As, Bs, acc);

    float* Sb = S + (size_t)bh * PP * PP;
#pragma unroll
    for (int mi = 0; mi < 4; ++mi)
#pragma unroll
        for (int r = 0; r < 4; ++r) {
            const int row = mt * 128 + wm * 64 + mi * 16 + quad * 4 + r;
#pragma unroll
            for (int ni = 0; ni < 4; ++ni) {
                const int col = nt * 128 + wn * 64 + ni * 16 + l16;
                Sb[(size_t)row * PP + col] = acc[mi][ni][r] * SCALE;
            }
        }
}

// ---------------------------------------------------------------------------
// Kernel 4: row softmax over S, writing normalized P as fp16 overlaid into
// S's storage (row pitch 1024 fp16 = 2048 B). One wave per row.
// ---------------------------------------------------------------------------
__global__ __launch_bounds__(256) void softmax_kernel(float* __restrict__ S)
{
    const int tid  = threadIdx.x;
    const int wave = tid >> 6;
    const int lane = tid & 63;
    const int row  = blockIdx.x * 4 + wave;
    float* rp = S + (size_t)row * PP;

    const float4 a = *(const float4*)(rp + lane * 8);
    const float4 b = *(const float4*)(rp + lane * 8 + 4);

    float m = fmaxf(fmaxf(fmaxf(a.x, a.y), fmaxf(a.z, a.w)),
                    fmaxf(fmaxf(b.x, b.y), fmaxf(b.z, b.w)));
#pragma unroll
    for (int off = 1; off < 64; off <<= 1) m = fmaxf(m, __shfl_xor(m, off, 64));

    float e[8];
    e[0] = expf(a.x - m); e[1] = expf(a.y - m);
    e[2] = expf(a.z - m); e[3] = expf(a.w - m);
    e[4] = expf(b.x - m); e[5] = expf(b.y - m);
    e[6] = expf(b.z - m); e[7] = expf(b.w - m);

    float sum = e[0] + e[1] + e[2] + e[3] + e[4] + e[5] + e[6] + e[7];
#pragma unroll
    for (int off = 1; off < 64; off <<= 1) sum += __shfl_xor(sum, off, 64);
    const float inv = 1.0f / sum;

    __syncthreads();   // order the fp16 stores after all float loads

    f16_t* prow = (f16_t*)rp;
    f16x8_t o;
#pragma unroll
    for (int j = 0; j < 8; ++j) o[j] = (_Float16)(e[j] * inv);
    *(f16x8_t*)(prow + lane * 8) = o;
}

// ---------------------------------------------------------------------------
// Kernel 5: O = P @ V per (b,h) -> out fp32 (b,c,p,t) (operand-swapped).
// A = vt [e][p] (M = e = 2048), Bt = P (N = p = 512), K = 512 (16 pipelined
// steps). D[row=e][col=p]: r advances along t -> one float4 16B store per
// (mi,ni). grid 2048 blocks 1D: bh = id&31, tile = id>>5.
// ---------------------------------------------------------------------------
__global__ __launch_bounds__(256) void pv_kernel(const f16_t* __restrict__ Pm,
                                                 const f16_t* __restrict__ vt,
                                                 float* __restrict__ out)
{
    __shared__ f16_t As[2 * 128 * 32];
    __shared__ f16_t Bs[2 * 128 * 32];
    const int id = blockIdx.x;
    const int bh = id & 31;
    const int tile = id >> 5;               // 0..63
    const int nt = tile & 3, mt = tile >> 2;
    const int tid  = threadIdx.x;
    const int lane = tid & 63;
    const int wave = tid >> 6;
    const int wm = wave & 1, wn = wave >> 1;
    const int quad = lane >> 4, l16 = lane & 15;

    f32x4_t acc[4][4];                      // [mi: e tiles][ni: p tiles]
#pragma unroll
    for (int i = 0; i < 4; ++i)
#pragma unroll
        for (int j = 0; j < 4; ++j) acc[i][j] = (f32x4_t){0.f, 0.f, 0.f, 0.f};

    const f16_t* Pb  = Pm + (size_t)bh * PP * 1024;
    const f16_t* vtb = vt + (size_t)bh * EE * PP;
    gemm_lds_bt_pipe(vtb, PP, Pb, 1024, PP, mt * 128, nt * 128, As, Bs, acc);

    const int b = bh >> 1, h = bh & 1;
#pragma unroll
    for (int mi = 0; mi < 4; ++mi) {
        const int e0 = mt * 128 + wm * 64 + mi * 16 + quad * 4;   // r = 0..3
        const int d  = e0 >> 5;
        const int t0 = e0 & 31;             // multiple of 4 -> 16B aligned
#pragma unroll
        for (int ni = 0; ni < 4; ++ni) {
            const int p = nt * 128 + wn * 64 + ni * 16 + l16;
            *(f32x4_t*)(out + ((size_t)(b * CC + h * DD + d) * PP + p) * TT + t0)
                = acc[mi][ni];
        }
    }
}

// ---------------------------------------------------------------------------
// Workspace layout (bytes):
//   [0,   64M)  q   fp16 [b][h][p][e]
//   [64M, 128M) k   fp16 [b][h][p][e]
//   [128M,192M) v   fp16 [b][h][p][e]
//   [192M,256M) vt  fp16 [b][h][e][p]
//   [256M,288M) S   fp32 [bh][i][j]  (P fp16 overlaid, row pitch 1024 elems)
//   Wh fp16 [384][128] parked at 256M (S region) -- consumed by proj before
//   qk_kernel overwrites it with S.
// ---------------------------------------------------------------------------
extern "C" void kernel_launch(void* const* d_in, const int* in_sizes, int n_in,
                              void* d_out, int out_size, void* d_ws, size_t ws_size,
                              hipStream_t stream)
{
    const float* x    = (const float*)d_in[0];
    const float* W    = (const float*)d_in[1];
    const float* bias = (const float*)d_in[2];
    float* out = (float*)d_out;

    char* ws = (char*)d_ws;
    const size_t MiB = 1024ull * 1024ull;
    f16_t* q  = (f16_t*)(ws);
    f16_t* k  = (f16_t*)(ws + 64 * MiB);
    f16_t* v  = (f16_t*)(ws + 128 * MiB);
    f16_t* vt = (f16_t*)(ws + 192 * MiB);
    float* S  = (float*)(ws + 256 * MiB);
    f16_t* Wh = (f16_t*)(ws + 256 * MiB);   // overlaid with S (safe: see above)

    wcvt_kernel<<<dim3(48), dim3(256), 0, stream>>>(W, Wh);
    proj_kernel<<<dim3(128, 16), dim3(256), 0, stream>>>(x, Wh, bias, q, k, v);
    vpose_kernel<<<dim3(256, 32), dim3(256), 0, stream>>>(v, vt);
    qk_kernel<<<dim3(512), dim3(256), 0, stream>>>(q, k, S);
    softmax_kernel<<<dim3(4096), dim3(256), 0, stream>>>(S);
    pv_kernel<<<dim3(2048), dim3(256), 0, stream>>>((const f16_t*)S, vt, out);
}